// Round 3
// baseline (1464.733 us; speedup 1.0000x reference)
//
#include <hip/hip_runtime.h>

#define B_ 16
#define N_ 4096
#define S_ 1024
#define K_ 32
#define PITCH2 136   // 128 + 8 shorts: b128 frag reads -> 2-way bank alias (free)
#define PITCH1 168   // 160 + 8 shorts

typedef unsigned long long u64;
typedef short bf16x8 __attribute__((ext_vector_type(8)));
typedef unsigned short u16x8 __attribute__((ext_vector_type(8)));
typedef float f32x4 __attribute__((ext_vector_type(4)));
typedef float f32x2 __attribute__((ext_vector_type(2)));

__device__ __forceinline__ unsigned short f2bf(float f) {
  unsigned u = __float_as_uint(f);
  unsigned r = (u + 0x7FFFu + ((u >> 16) & 1u)) >> 16;
  return (unsigned short)r;
}
__device__ __forceinline__ float bf2f(unsigned short h) {
  return __uint_as_float(((unsigned)h) << 16);
}

// DPP wave64 max reduce: shr1,2,4,8 + bcast15 + bcast31 -> lane 63 = wave max
#define DPP_MAXF(v, ctrl)                                                       \
  {                                                                             \
    int _t = __builtin_amdgcn_update_dpp(__float_as_int(v), __float_as_int(v),  \
                                         ctrl, 0xf, 0xf, false);                \
    v = fmaxf(v, __int_as_float(_t));                                           \
  }

// ===== fused front kernel: blocks 0-15 FPS | 16-31 init | 32+ transpose =====
// FPS: proven 8-wave x 8-pts/lane config (r1/r2 lesson: fewer waves + more
// per-lane serial work loses). Chain cuts vs the 650us baseline:
//  - no sequential argmax: pure min-update + packed-max tree; the index scan
//    and coord-extract tree depend only on bestv -> they hide under DPP.
//  - owner exchanges coords WITH the key: one LDS window per iter, no
//    dependent pts[cur] round-trip; 3-level key reduce instead of 7-chain.
__global__ __launch_bounds__(512) void k_front(
    const float* __restrict__ xyz, float* __restrict__ new_xyz,
    const float* __restrict__ feat, unsigned short* __restrict__ featT,
    const float* __restrict__ w0, const float* __restrict__ w1,
    const float* __restrict__ w2, unsigned short* __restrict__ wbf0,
    unsigned short* __restrict__ wbf1, unsigned short* __restrict__ wbf2,
    float* __restrict__ stats) {
  __shared__ __align__(16) float smem[N_ * 4 + S_ + 128];
  int blk = blockIdx.x, t = threadIdx.x;

  if (blk < 16) {
#pragma clang fp contract(off)
#if __has_builtin(__builtin_amdgcn_s_setprio)
    __builtin_amdgcn_s_setprio(3);
#endif
    float4* pts = (float4*)smem;
    int* idxs = (int*)(smem + N_ * 4);
    u64* swk = (u64*)(smem + N_ * 4 + S_);            // 2 parity x 8 keys
    float4* swc = (float4*)(smem + N_ * 4 + S_ + 32); // 2 parity x 8 coords
    int b = blk;
    const float* base = xyz + (size_t)b * N_ * 3;
    for (int i = t; i < N_; i += 512)
      pts[i] = make_float4(base[i * 3], base[i * 3 + 1], base[i * 3 + 2], 0.0f);
    if (t == 0) idxs[0] = 0;
    __syncthreads();

    int w = t >> 6, L = t & 63;
    int i0 = t * 8;   // lane-chunked: lane owns points [t*8, t*8+8)
    f32x2 px[4], py[4], pz[4], pd[4];
    #pragma unroll
    for (int j = 0; j < 4; ++j) {
      float4 p = pts[i0 + 2 * j], q = pts[i0 + 2 * j + 1];
      px[j] = (f32x2){p.x, q.x};
      py[j] = (f32x2){p.y, q.y};
      pz[j] = (f32x2){p.z, q.z};
      pd[j] = (f32x2){1e10f, 1e10f};
    }
    float4 c = pts[0];   // first centroid = point 0
    for (int it = 0; it < S_; ++it) {
      f32x2 c2x = (f32x2){c.x, c.x};
      f32x2 c2y = (f32x2){c.y, c.y};
      f32x2 c2z = (f32x2){c.z, c.z};
      // pure min-update (bit-identical formula/order, contract off)
      #pragma unroll
      for (int j = 0; j < 4; ++j) {
        f32x2 dx = px[j] - c2x;
        f32x2 dy = py[j] - c2y;
        f32x2 dz = pz[j] - c2z;
        f32x2 d = (dx * dx + dy * dy) + dz * dz;
        pd[j] = __builtin_elementwise_min(pd[j], d);
      }
      // per-lane max: 3-level tree (short chain, no serial argmax)
      f32x2 m0 = __builtin_elementwise_max(pd[0], pd[1]);
      f32x2 m1 = __builtin_elementwise_max(pd[2], pd[3]);
      f32x2 m2 = __builtin_elementwise_max(m0, m1);
      float bestv = fmaxf(m2.x, m2.y);
      // first-match index scan vs OWN max (always exists; smallest e wins ->
      // jnp.argmax tie-break). Depends only on bestv -> overlaps DPP below.
      int a0 = (pd[0].x == bestv) ? 0 : 8;
      int a1 = (pd[0].y == bestv) ? 1 : 8;
      int a2 = (pd[1].x == bestv) ? 2 : 8;
      int a3 = (pd[1].y == bestv) ? 3 : 8;
      int a4 = (pd[2].x == bestv) ? 4 : 8;
      int a5 = (pd[2].y == bestv) ? 5 : 8;
      int a6 = (pd[3].x == bestv) ? 6 : 8;
      int a7 = (pd[3].y == bestv) ? 7 : 8;
      int e = min(min(min(a0, a1), min(a2, a3)), min(min(a4, a5), min(a6, a7)));
      // speculative coord extract from own registers (also overlaps DPP)
      int half = e & 1, pr = e >> 1;
      f32x2 sx0 = (pr & 1) ? px[1] : px[0], sx1 = (pr & 1) ? px[3] : px[2];
      f32x2 sxp = (pr & 2) ? sx1 : sx0;
      float cxl = half ? sxp.y : sxp.x;
      f32x2 sy0 = (pr & 1) ? py[1] : py[0], sy1 = (pr & 1) ? py[3] : py[2];
      f32x2 syp = (pr & 2) ? sy1 : sy0;
      float cyl = half ? syp.y : syp.x;
      f32x2 sz0 = (pr & 1) ? pz[1] : pz[0], sz1 = (pr & 1) ? pz[3] : pz[2];
      f32x2 szp = (pr & 2) ? sz1 : sz0;
      float czl = half ? szp.y : szp.x;
      // wave max (exact bit value of some lane's bestv)
      float v = bestv;
      DPP_MAXF(v, 0x111);
      DPP_MAXF(v, 0x112);
      DPP_MAXF(v, 0x114);
      DPP_MAXF(v, 0x118);
      DPP_MAXF(v, 0x142);
      DPP_MAXF(v, 0x143);
      float wmax = __int_as_float(__builtin_amdgcn_readlane(__float_as_int(v), 63));
      u64 mask = __ballot(bestv == wmax);
      int owner = __ffsll((long long)mask) - 1;   // lowest lane = smallest idx
      int par = (it & 1) * 8;
      if (L == owner) {
        // key: larger dist wins; tie -> larger (4095-idx) = smaller idx
        swk[par + w] = ((u64)__float_as_uint(wmax) << 32) |
                       (unsigned)(4095 - (i0 + e));
        swc[par + w] = make_float4(cxl, cyl, czl, 0.0f);
      }
      __syncthreads();
      // ONE LDS window: 8 keys + 8 coord slots (all broadcast reads), then
      // a 3-level select tree carrying coords alongside keys.
      u64 k0 = swk[par + 0], k1 = swk[par + 1], k2 = swk[par + 2], k3 = swk[par + 3];
      u64 k4 = swk[par + 4], k5 = swk[par + 5], k6 = swk[par + 6], k7 = swk[par + 7];
      float4 c0 = swc[par + 0], c1 = swc[par + 1], c2 = swc[par + 2], c3 = swc[par + 3];
      float4 c4 = swc[par + 4], c5 = swc[par + 5], c6 = swc[par + 6], c7 = swc[par + 7];
      bool s01 = k0 > k1, s23 = k2 > k3, s45 = k4 > k5, s67 = k6 > k7;
      u64 ka = s01 ? k0 : k1;  float4 ca = s01 ? c0 : c1;
      u64 kb = s23 ? k2 : k3;  float4 cb = s23 ? c2 : c3;
      u64 kc = s45 ? k4 : k5;  float4 cg = s45 ? c4 : c5;
      u64 kd = s67 ? k6 : k7;  float4 ch = s67 ? c6 : c7;
      bool sab = ka > kb, scd = kc > kd;
      u64 ke = sab ? ka : kb;  float4 ce = sab ? ca : cb;
      u64 kf2 = scd ? kc : kd; float4 cf = scd ? cg : ch;
      bool sef = ke > kf2;
      u64 kf = sef ? ke : kf2;
      c = sef ? ce : cf;
      if (t == 0 && it + 1 < S_)
        idxs[it + 1] = 4095 - (int)(unsigned)(kf & 0xFFFFFFFFull);
    }
    __syncthreads();
    for (int i = t; i < S_; i += 512) {
      float4 v = pts[idxs[i]];
      size_t o = ((size_t)b * S_ + i) * 3;
      new_xyz[o] = v.x; new_xyz[o + 1] = v.y; new_xyz[o + 2] = v.z;
    }
  } else if (blk < 32) {
    int id = (blk - 16) * 512 + t;
    const int st = 16 * 512;
    for (int i = id; i < 32768; i += st) stats[i] = 0.0f;
    for (int i = id; i < 128 * 160; i += st) {
      int n = i / 160, k = i - n * 160;
      float v = (k < 128) ? w0[n * 131 + 3 + k] : (k < 131) ? w0[n * 131 + k - 128] : 0.0f;
      wbf0[i] = f2bf(v);
    }
    for (int i = id; i < 128 * 128; i += st) wbf1[i] = f2bf(w1[i]);
    for (int i = id; i < 256 * 128; i += st) wbf2[i] = f2bf(w2[i]);
  } else {
    float (*tile)[33] = (float(*)[33])smem;
    int blk2 = blk - 32;
    int n0 = (blk2 & 127) * 32;
    int c0 = ((blk2 >> 7) & 3) * 32;
    int b = blk2 >> 9;
    int tx = t & 31, ty = t >> 5;
    #pragma unroll
    for (int j = 0; j < 32; j += 16)
      tile[ty + j][tx] = feat[((size_t)b * 128 + c0 + ty + j) * N_ + n0 + tx];
    __syncthreads();
    #pragma unroll
    for (int j = 0; j < 32; j += 16)
      featT[((size_t)b * N_ + n0 + ty + j) * 128 + c0 + tx] = f2bf(tile[tx][ty + j]);
  }
}

// ---------------- ball query (standalone; bit-exact formula) ----------------
__global__ __launch_bounds__(256) void k_ballq(const float* __restrict__ xyz,
                                               const float* __restrict__ new_xyz,
                                               int* __restrict__ ball_idx) {
  int b = blockIdx.y;
  int s = blockIdx.x * 4 + (threadIdx.x >> 6);
  int lane = threadIdx.x & 63;
  const float* pb = xyz + (size_t)b * N_ * 3;
  size_t q = (size_t)b * S_ + s;
  float qx = new_xyz[q * 3], qy = new_xyz[q * 3 + 1], qz = new_xyz[q * 3 + 2];
  float sq = __fadd_rn(__fadd_rn(__fmul_rn(qx, qx), __fmul_rn(qy, qy)), __fmul_rn(qz, qz));
  int* out = ball_idx + q * K_;
  int total = 0;
  int first_idx = -1;
  for (int basei = 0; basei < N_; basei += 64) {
    int i = basei + lane;
    float fx = pb[i * 3], fy = pb[i * 3 + 1], fz = pb[i * 3 + 2];
    float dot = __fmul_rn(qx, fx);
    dot = __fadd_rn(dot, __fmul_rn(qy, fy));
    dot = __fadd_rn(dot, __fmul_rn(qz, fz));
    float sd = __fadd_rn(__fadd_rn(__fmul_rn(fx, fx), __fmul_rn(fy, fy)), __fmul_rn(fz, fz));
    float dist = __fadd_rn(__fadd_rn(__fmul_rn(-2.0f, dot), sq), sd);
    bool within = (dist <= 0.36f);
    u64 m = __ballot(within);
    if (first_idx < 0 && m) first_idx = basei + __ffsll((long long)m) - 1;
    if (within) {
      int pos = total + __popcll(m & ((1ull << lane) - 1ull));
      if (pos < K_) out[pos] = i;
    }
    total += (int)__popcll(m);
    if (total >= K_) break;
  }
  if (total < K_) {
    int k2 = total + lane;
    if (k2 < K_) out[k2] = first_idx;
  }
}

// ==== MFMA layer kernels — persistent blocks: W/murs staged ONCE, then a
// barrier-free tile loop (A lives in registers since r10) ====
#define MFMA(a, b, c) __builtin_amdgcn_mfma_f32_16x16x32_bf16(a, b, c, 0, 0, 0)
#define NTILES 4096   // 16 batches x 256 s0-tiles

// ---- layer 1: gather(reg) + matmul K=131(pad160)->128 ----
__global__ __launch_bounds__(256) void k_layer1(
    const float* __restrict__ xyz, const float* __restrict__ new_xyz,
    const unsigned short* __restrict__ featT, const int* __restrict__ ball_idx,
    const unsigned short* __restrict__ wbf0, const float* __restrict__ b0,
    unsigned short* __restrict__ y, float* __restrict__ stats) {
  __shared__ __align__(16) unsigned short Wl[128 * PITCH1];   // 42 KB, W only
  __shared__ float sbias[128];
  int t = threadIdx.x;
  int w = t >> 6, L = t & 63, lm = L & 15, lg = L >> 4;
  {
    int n = t >> 1, h = t & 1;
    const uint4* wr = (const uint4*)(wbf0 + n * 160 + h * 80);
    uint4* wl = (uint4*)(Wl + n * PITCH1 + h * 80);
    #pragma unroll
    for (int i = 0; i < 10; ++i) wl[i] = wr[i];
    if (t < 128) sbias[t] = b0[t];
  }
  __syncthreads();

  for (int tile = blockIdx.x; tile < NTILES; tile += gridDim.x) {
    int bb = tile >> 8;
    int s0 = (tile & 255) * 4;
    size_t qg = (size_t)bb * S_ + s0 + w;

    int p0 = ball_idx[qg * K_ + lm];
    int p1 = ball_idx[qg * K_ + 16 + lm];
    const unsigned short* f0 = featT + ((size_t)bb * N_ + p0) * 128;
    const unsigned short* f1 = featT + ((size_t)bb * N_ + p1) * 128;
    bf16x8 a0[5], a1[5];
    #pragma unroll
    for (int kt = 0; kt < 4; ++kt) {
      a0[kt] = *(const bf16x8*)(f0 + kt * 32 + lg * 8);
      a1[kt] = *(const bf16x8*)(f1 + kt * 32 + lg * 8);
    }
    a0[4] = (bf16x8){0, 0, 0, 0, 0, 0, 0, 0};
    a1[4] = (bf16x8){0, 0, 0, 0, 0, 0, 0, 0};
    if (lg == 0) {
      float nx = new_xyz[qg * 3], ny = new_xyz[qg * 3 + 1], nz = new_xyz[qg * 3 + 2];
      const float* pp0 = xyz + ((size_t)bb * N_ + p0) * 3;
      const float* pp1 = xyz + ((size_t)bb * N_ + p1) * 3;
      a0[4][0] = (short)f2bf(pp0[0] - nx);
      a0[4][1] = (short)f2bf(pp0[1] - ny);
      a0[4][2] = (short)f2bf(pp0[2] - nz);
      a1[4][0] = (short)f2bf(pp1[0] - nx);
      a1[4][1] = (short)f2bf(pp1[1] - ny);
      a1[4][2] = (short)f2bf(pp1[2] - nz);
    }
    f32x4 acc[2][8];
    #pragma unroll
    for (int mi = 0; mi < 2; ++mi)
      #pragma unroll
      for (int nt = 0; nt < 8; ++nt) acc[mi][nt] = (f32x4){0.f, 0.f, 0.f, 0.f};
    #pragma unroll
    for (int kt = 0; kt < 5; ++kt) {
      int ko = kt * 32 + lg * 8;
      bf16x8 bv[8];
      #pragma unroll
      for (int nt = 0; nt < 8; ++nt)
        bv[nt] = *(const bf16x8*)&Wl[(nt * 16 + lm) * PITCH1 + ko];
      #pragma unroll
      for (int nt = 0; nt < 8; ++nt) {
        acc[0][nt] = MFMA(a0[kt], bv[nt], acc[0][nt]);
        acc[1][nt] = MFMA(a1[kt], bv[nt], acc[1][nt]);
      }
    }
    int slot = tile & 31;
    #pragma unroll
    for (int nt = 0; nt < 8; ++nt) {
      int col = nt * 16 + lm;
      float bo = sbias[col];
      float s1 = 0.f, s2 = 0.f;
      #pragma unroll
      for (int mi = 0; mi < 2; ++mi)
        #pragma unroll
        for (int r = 0; r < 4; ++r) {
          float yv = acc[mi][nt][r] + bo;
          s1 += yv; s2 += yv * yv;
          int ks = mi * 16 + lg * 4 + r;
          y[(qg * K_ + ks) * 128 + col] = f2bf(yv);
        }
      s1 += __shfl_xor(s1, 16); s2 += __shfl_xor(s2, 16);
      s1 += __shfl_xor(s1, 32); s2 += __shfl_xor(s2, 32);
      if (lg == 0) {
        atomicAdd(stats + ((size_t)slot * 128 + col) * 2, s1);
        atomicAdd(stats + ((size_t)slot * 128 + col) * 2 + 1, s2);
      }
    }
  }
}

// ---- layer 2: murs fold + BN+relu(reg) + matmul 128->128, y IN-PLACE ----
__global__ __launch_bounds__(256) void k_layer2(
    unsigned short* y, const float* __restrict__ stats,
    const float* __restrict__ gamma, const float* __restrict__ beta,
    const unsigned short* __restrict__ wbf1, const float* __restrict__ b1,
    float* __restrict__ stats2) {
  __shared__ __align__(16) unsigned short Wl[128 * PITCH2];   // 34 KB, W only
  __shared__ __align__(16) float sa[128], sd[128];
  __shared__ float sbias[128];
  int t = threadIdx.x;
  int w = t >> 6, L = t & 63, lm = L & 15, lg = L >> 4;
  if (t < 128) {
    float s1 = 0.0f, s2 = 0.0f;
    for (int sl = 0; sl < 32; ++sl) {
      s1 += stats[((size_t)sl * 128 + t) * 2];
      s2 += stats[((size_t)sl * 128 + t) * 2 + 1];
    }
    const float inv = 1.0f / 524288.0f;
    float mu = s1 * inv;
    float var = s2 * inv - mu * mu;
    float a = gamma[t] * rsqrtf(var + 1e-5f);
    sa[t] = a;
    sd[t] = beta[t] - a * mu;
    sbias[t] = b1[t];
  }
  {
    int n = t >> 1, h = t & 1;
    const uint4* wr = (const uint4*)(wbf1 + n * 128 + h * 64);
    uint4* wl = (uint4*)(Wl + n * PITCH2 + h * 64);
    #pragma unroll
    for (int i = 0; i < 8; ++i) wl[i] = wr[i];
  }
  __syncthreads();

  for (int tile = blockIdx.x; tile < NTILES; tile += gridDim.x) {
    int bb = tile >> 8;
    int s0 = (tile & 255) * 4;
    size_t qg = (size_t)bb * S_ + s0 + w;

    const u16x8* yr0 = (const u16x8*)(y + (qg * K_ + lm) * 128);
    const u16x8* yr1 = (const u16x8*)(y + (qg * K_ + 16 + lm) * 128);
    u16x8 raw0[4], raw1[4];
    #pragma unroll
    for (int kt = 0; kt < 4; ++kt) { raw0[kt] = yr0[kt * 4 + lg]; raw1[kt] = yr1[kt * 4 + lg]; }
    bf16x8 a0[4], a1[4];
    #pragma unroll
    for (int kt = 0; kt < 4; ++kt) {
      int c = kt * 32 + lg * 8;
      f32x4 A0 = *(const f32x4*)&sa[c], A1 = *(const f32x4*)&sa[c + 4];
      f32x4 D0 = *(const f32x4*)&sd[c], D1 = *(const f32x4*)&sd[c + 4];
      #pragma unroll
      for (int j = 0; j < 4; ++j) {
        a0[kt][j]     = (short)f2bf(fmaxf(A0[j] * bf2f(raw0[kt][j])     + D0[j], 0.f));
        a0[kt][j + 4] = (short)f2bf(fmaxf(A1[j] * bf2f(raw0[kt][j + 4]) + D1[j], 0.f));
        a1[kt][j]     = (short)f2bf(fmaxf(A0[j] * bf2f(raw1[kt][j])     + D0[j], 0.f));
        a1[kt][j + 4] = (short)f2bf(fmaxf(A1[j] * bf2f(raw1[kt][j + 4]) + D1[j], 0.f));
      }
    }
    f32x4 acc[2][8];
    #pragma unroll
    for (int mi = 0; mi < 2; ++mi)
      #pragma unroll
      for (int nt = 0; nt < 8; ++nt) acc[mi][nt] = (f32x4){0.f, 0.f, 0.f, 0.f};
    #pragma unroll
    for (int kt = 0; kt < 4; ++kt) {
      int ko = kt * 32 + lg * 8;
      bf16x8 bv[8];
      #pragma unroll
      for (int nt = 0; nt < 8; ++nt)
        bv[nt] = *(const bf16x8*)&Wl[(nt * 16 + lm) * PITCH2 + ko];
      #pragma unroll
      for (int nt = 0; nt < 8; ++nt) {
        acc[0][nt] = MFMA(a0[kt], bv[nt], acc[0][nt]);
        acc[1][nt] = MFMA(a1[kt], bv[nt], acc[1][nt]);
      }
    }
    int slot = tile & 31;
    #pragma unroll
    for (int nt = 0; nt < 8; ++nt) {
      int col = nt * 16 + lm;
      float bo = sbias[col];
      float s1 = 0.f, s2 = 0.f;
      #pragma unroll
      for (int mi = 0; mi < 2; ++mi)
        #pragma unroll
        for (int r = 0; r < 4; ++r) {
          float yv = acc[mi][nt][r] + bo;
          s1 += yv; s2 += yv * yv;
          int ks = mi * 16 + lg * 4 + r;
          y[(qg * K_ + ks) * 128 + col] = f2bf(yv);
        }
      s1 += __shfl_xor(s1, 16); s2 += __shfl_xor(s2, 16);
      s1 += __shfl_xor(s1, 32); s2 += __shfl_xor(s2, 32);
      if (lg == 0) {
        atomicAdd(stats2 + ((size_t)slot * 128 + col) * 2, s1);
        atomicAdd(stats2 + ((size_t)slot * 128 + col) * 2 + 1, s2);
      }
    }
  }
}

// ---- layer 3: murs fold + BN+relu(reg) + matmul 128->256 (nh per block.y) ----
__global__ __launch_bounds__(256) void k_layer3(
    const unsigned short* __restrict__ y, const float* __restrict__ stats2,
    const float* __restrict__ gamma, const float* __restrict__ beta,
    const unsigned short* __restrict__ wbf2, const float* __restrict__ b2,
    unsigned short* __restrict__ ymax, unsigned short* __restrict__ ymin,
    float* __restrict__ stats3) {
  __shared__ __align__(16) unsigned short Wl[128 * PITCH2];
  __shared__ __align__(16) float sa[128], sd[128];
  __shared__ float sbias[128];
  int nh = blockIdx.y, t = threadIdx.x;
  int w = t >> 6, L = t & 63, lm = L & 15, lg = L >> 4;
  if (t < 128) {
    float s1 = 0.0f, s2 = 0.0f;
    for (int sl = 0; sl < 32; ++sl) {
      s1 += stats2[((size_t)sl * 128 + t) * 2];
      s2 += stats2[((size_t)sl * 128 + t) * 2 + 1];
    }
    const float inv = 1.0f / 524288.0f;
    float mu = s1 * inv;
    float var = s2 * inv - mu * mu;
    float a = gamma[t] * rsqrtf(var + 1e-5f);
    sa[t] = a;
    sd[t] = beta[t] - a * mu;
    sbias[t] = b2[nh * 128 + t];
  }
  {
    int n = t >> 1, h = t & 1;
    const uint4* wr = (const uint4*)(wbf2 + (size_t)(nh * 128 + n) * 128 + h * 64);
    uint4* wl = (uint4*)(Wl + n * PITCH2 + h * 64);
    #pragma unroll
    for (int i = 0; i < 8; ++i) wl[i] = wr[i];
  }
  __syncthreads();

  for (int tile = blockIdx.x; tile < NTILES; tile += gridDim.x) {
    int bb = tile >> 8;
    int s0 = (tile & 255) * 4;
    size_t qg = (size_t)bb * S_ + s0 + w;

    const u16x8* yr0 = (const u16x8*)(y + (qg * K_ + lm) * 128);
    const u16x8* yr1 = (const u16x8*)(y + (qg * K_ + 16 + lm) * 128);
    u16x8 raw0[4], raw1[4];
    #pragma unroll
    for (int kt = 0; kt < 4; ++kt) { raw0[kt] = yr0[kt * 4 + lg]; raw1[kt] = yr1[kt * 4 + lg]; }
    bf16x8 a0[4], a1[4];
    #pragma unroll
    for (int kt = 0; kt < 4; ++kt) {
      int c = kt * 32 + lg * 8;
      f32x4 A0 = *(const f32x4*)&sa[c], A1 = *(const f32x4*)&sa[c + 4];
      f32x4 D0 = *(const f32x4*)&sd[c], D1 = *(const f32x4*)&sd[c + 4];
      #pragma unroll
      for (int j = 0; j < 4; ++j) {
        a0[kt][j]     = (short)f2bf(fmaxf(A0[j] * bf2f(raw0[kt][j])     + D0[j], 0.f));
        a0[kt][j + 4] = (short)f2bf(fmaxf(A1[j] * bf2f(raw0[kt][j + 4]) + D1[j], 0.f));
        a1[kt][j]     = (short)f2bf(fmaxf(A0[j] * bf2f(raw1[kt][j])     + D0[j], 0.f));
        a1[kt][j + 4] = (short)f2bf(fmaxf(A1[j] * bf2f(raw1[kt][j + 4]) + D1[j], 0.f));
      }
    }
    f32x4 acc[2][8];
    #pragma unroll
    for (int mi = 0; mi < 2; ++mi)
      #pragma unroll
      for (int nt = 0; nt < 8; ++nt) acc[mi][nt] = (f32x4){0.f, 0.f, 0.f, 0.f};
    #pragma unroll
    for (int kt = 0; kt < 4; ++kt) {
      int ko = kt * 32 + lg * 8;
      bf16x8 bv[8];
      #pragma unroll
      for (int nt = 0; nt < 8; ++nt)
        bv[nt] = *(const bf16x8*)&Wl[(nt * 16 + lm) * PITCH2 + ko];
      #pragma unroll
      for (int nt = 0; nt < 8; ++nt) {
        acc[0][nt] = MFMA(a0[kt], bv[nt], acc[0][nt]);
        acc[1][nt] = MFMA(a1[kt], bv[nt], acc[1][nt]);
      }
    }
    int slot = tile & 31;
    #pragma unroll
    for (int nt = 0; nt < 8; ++nt) {
      int col = nt * 16 + lm;
      int o = nh * 128 + col;
      float bo = sbias[col];
      float s1 = 0.f, s2 = 0.f, mx = -3.4e38f, mn = 3.4e38f;
      #pragma unroll
      for (int mi = 0; mi < 2; ++mi)
        #pragma unroll
        for (int r = 0; r < 4; ++r) {
          float yv = acc[mi][nt][r] + bo;
          s1 += yv; s2 += yv * yv;
          mx = fmaxf(mx, yv); mn = fminf(mn, yv);
        }
      s1 += __shfl_xor(s1, 16); s2 += __shfl_xor(s2, 16);
      s1 += __shfl_xor(s1, 32); s2 += __shfl_xor(s2, 32);
      mx = fmaxf(mx, __shfl_xor(mx, 16)); mx = fmaxf(mx, __shfl_xor(mx, 32));
      mn = fminf(mn, __shfl_xor(mn, 16)); mn = fminf(mn, __shfl_xor(mn, 32));
      if (lg == 0) {
        ymax[qg * 256 + o] = f2bf(mx);
        ymin[qg * 256 + o] = f2bf(mn);
        atomicAdd(stats3 + ((size_t)slot * 256 + o) * 2, s1);
        atomicAdd(stats3 + ((size_t)slot * 256 + o) * 2 + 1, s2);
      }
    }
  }
}

// -------- final: murs fold + select extreme by sign(a) + BN+relu + transpose --------
__global__ __launch_bounds__(256) void k_final(const unsigned short* __restrict__ ymax,
                                               const unsigned short* __restrict__ ymin,
                                               const float* __restrict__ stats3,
                                               const float* __restrict__ gamma,
                                               const float* __restrict__ beta,
                                               float* __restrict__ out2) {
  __shared__ float tile[32][33];
  __shared__ float smA[32], smD[32];
  int b = blockIdx.z, o0 = blockIdx.y * 32, s0 = blockIdx.x * 32;
  int tx = threadIdx.x, ty = threadIdx.y;
  if (ty == 0) {
    int c = o0 + tx;
    float s1 = 0.0f, s2 = 0.0f;
    for (int sl = 0; sl < 32; ++sl) {
      s1 += stats3[((size_t)sl * 256 + c) * 2];
      s2 += stats3[((size_t)sl * 256 + c) * 2 + 1];
    }
    const float inv = 1.0f / 524288.0f;
    float mu = s1 * inv;
    float var = s2 * inv - mu * mu;
    float a = gamma[c] * rsqrtf(var + 1e-5f);
    smA[tx] = a;
    smD[tx] = beta[c] - a * mu;
  }
  __syncthreads();
  float a_rd = smA[tx];
  #pragma unroll
  for (int j = 0; j < 32; j += 8) {
    size_t src = ((size_t)b * S_ + s0 + ty + j) * 256 + o0 + tx;
    tile[ty + j][tx] = (a_rd >= 0.0f) ? bf2f(ymax[src]) : bf2f(ymin[src]);
  }
  __syncthreads();
  #pragma unroll
  for (int j = 0; j < 32; j += 8) {
    float a = smA[ty + j], dd = smD[ty + j];
    out2[((size_t)b * 256 + o0 + ty + j) * S_ + s0 + tx] = fmaxf(a * tile[tx][ty + j] + dd, 0.0f);
  }
}

extern "C" void kernel_launch(void* const* d_in, const int* in_sizes, int n_in,
                              void* d_out, int out_size, void* d_ws, size_t ws_size,
                              hipStream_t stream) {
  (void)in_sizes; (void)n_in; (void)out_size; (void)ws_size;
  const float* xyz  = (const float*)d_in[0];
  const float* feat = (const float*)d_in[1];
  const float* w0   = (const float*)d_in[2];
  const float* b0   = (const float*)d_in[3];
  const float* ga0  = (const float*)d_in[4];
  const float* be0  = (const float*)d_in[5];
  const float* w1   = (const float*)d_in[6];
  const float* b1   = (const float*)d_in[7];
  const float* ga1  = (const float*)d_in[8];
  const float* be1  = (const float*)d_in[9];
  const float* w2   = (const float*)d_in[10];
  const float* b2   = (const float*)d_in[11];
  const float* ga2  = (const float*)d_in[12];
  const float* be2  = (const float*)d_in[13];

  float* out_xyz  = (float*)d_out;
  float* out_feat = out_xyz + (size_t)B_ * S_ * 3;

  char* ws = (char*)d_ws;
  size_t off = 0;
  auto alloc = [&](size_t bytes) -> void* {
    void* p = ws + off;
    off += (bytes + 255) & ~(size_t)255;
    return p;
  };
  unsigned short* featT = (unsigned short*)alloc((size_t)B_ * N_ * 128 * 2);  // 16.8 MB bf16
  int*   ball  = (int*)alloc((size_t)B_ * S_ * K_ * 4);                       // 2.1 MB
  float* stats = (float*)alloc(32768 * 4);
  unsigned short* wbf0 = (unsigned short*)alloc(128 * 160 * 2);
  unsigned short* wbf1 = (unsigned short*)alloc(128 * 128 * 2);
  unsigned short* wbf2 = (unsigned short*)alloc(256 * 128 * 2);
  unsigned short* ymaxb = (unsigned short*)alloc((size_t)B_ * S_ * 256 * 2);  // 8.4 MB
  unsigned short* yminb = (unsigned short*)alloc((size_t)B_ * S_ * 256 * 2);  // 8.4 MB
  unsigned short* y = (unsigned short*)alloc((size_t)B_ * S_ * K_ * 128 * 2); // 134 MB

  // blocks: 16 fps (8 waves, 8 pts/lane) | 16 init | 8192 transpose
  k_front<<<16 + 16 + 8192, 512, 0, stream>>>(xyz, out_xyz, feat, featT,
                                              w0, w1, w2, wbf0, wbf1, wbf2, stats);
  k_ballq<<<dim3(256, 16), 256, 0, stream>>>(xyz, out_xyz, ball);
  // persistent grids: layer1 3 blocks/CU (43KB LDS), layer2 4/CU, layer3 (512,2)
  k_layer1<<<768, 256, 0, stream>>>(xyz, out_xyz, featT, ball, wbf0, b0, y, stats);
  k_layer2<<<1024, 256, 0, stream>>>(y, stats, ga0, be0, wbf1, b1, stats + 8192);
  k_layer3<<<dim3(512, 2), 256, 0, stream>>>(y, stats + 8192, ga1, be1, wbf2, b2,
                                             ymaxb, yminb, stats + 16384);
  k_final<<<dim3(32, 8, 16), dim3(32, 8), 0, stream>>>(ymaxb, yminb, stats + 16384,
                                                       ga2, be2, out_feat);
}

// Round 4
// 1085.240 us; speedup vs baseline: 1.3497x; 1.3497x over previous
//
#include <hip/hip_runtime.h>

#define B_ 16
#define N_ 4096
#define S_ 1024
#define K_ 32
#define PITCH2 136   // 128 + 8 shorts: b128 frag reads -> 2-way bank alias (free)
#define PITCH1 168   // 160 + 8 shorts

typedef unsigned long long u64;
typedef unsigned long long u64x2 __attribute__((ext_vector_type(2)));
typedef short bf16x8 __attribute__((ext_vector_type(8)));
typedef unsigned short u16x8 __attribute__((ext_vector_type(8)));
typedef float f32x4 __attribute__((ext_vector_type(4)));
typedef float f32x2 __attribute__((ext_vector_type(2)));

__device__ __forceinline__ unsigned short f2bf(float f) {
  unsigned u = __float_as_uint(f);
  unsigned r = (u + 0x7FFFu + ((u >> 16) & 1u)) >> 16;
  return (unsigned short)r;
}
__device__ __forceinline__ float bf2f(unsigned short h) {
  return __uint_as_float(((unsigned)h) << 16);
}

// DPP wave64 max reduce: shr1,2,4,8 + bcast15 + bcast31 -> lane 63 = wave max
#define DPP_MAX(v, ctrl)                                                        \
  {                                                                             \
    int _t = __builtin_amdgcn_update_dpp(__float_as_int(v), __float_as_int(v),  \
                                         ctrl, 0xf, 0xf, false);                \
    v = fmaxf(v, __int_as_float(_t));                                           \
  }

// ===== fused front kernel: blocks 0-15 FPS | 16-31 init | 32+ transpose =====
// FPS: proven R0 structure (8 waves x 8 pts/lane, serial argmax interleaved
// with the min-update, lane-0 key write, one barrier, pts[cur] at loop top).
// r3 lesson: the LDS pipe (shared by all 8 waves, ~10cy/instr) dominates the
// iteration period -> minimize LDS instruction count. Only change vs R0:
// keys read as 4x ds_read_b128 (u64x2) + 3-level tree instead of 8x b64 +
// 7-deep serial chain.
__global__ __launch_bounds__(512) void k_front(
    const float* __restrict__ xyz, float* __restrict__ new_xyz,
    const float* __restrict__ feat, unsigned short* __restrict__ featT,
    const float* __restrict__ w0, const float* __restrict__ w1,
    const float* __restrict__ w2, unsigned short* __restrict__ wbf0,
    unsigned short* __restrict__ wbf1, unsigned short* __restrict__ wbf2,
    float* __restrict__ stats) {
  __shared__ __align__(16) float smem[N_ * 4 + S_ + 64];
  int blk = blockIdx.x, t = threadIdx.x;

  if (blk < 16) {
#pragma clang fp contract(off)
#if __has_builtin(__builtin_amdgcn_s_setprio)
    __builtin_amdgcn_s_setprio(3);
#endif
    float4* pts = (float4*)smem;
    int* idxs = (int*)(smem + N_ * 4);
    u64* swk = (u64*)(smem + N_ * 4 + S_);
    int b = blk;
    const float* base = xyz + (size_t)b * N_ * 3;
    for (int i = t; i < N_; i += 512)
      pts[i] = make_float4(base[i * 3], base[i * 3 + 1], base[i * 3 + 2], 0.0f);
    if (t == 0) idxs[0] = 0;
    __syncthreads();
    f32x2 px[4], py[4], pz[4], pd[4];
    int i0 = t * 8;
    #pragma unroll
    for (int j = 0; j < 4; ++j) {
      float4 p0 = pts[i0 + 2 * j], p1 = pts[i0 + 2 * j + 1];
      px[j] = (f32x2){p0.x, p1.x};
      py[j] = (f32x2){p0.y, p1.y};
      pz[j] = (f32x2){p0.z, p1.z};
      pd[j] = (f32x2){1e10f, 1e10f};
    }
    int cur = 0;
    for (int it = 0; it < S_; ++it) {
      float4 c = pts[cur];
      f32x2 c2x = (f32x2){c.x, c.x}, c2y = (f32x2){c.y, c.y}, c2z = (f32x2){c.z, c.z};
      float bestv = -1.0f; int besti = 0;
      #pragma unroll
      for (int j = 0; j < 4; ++j) {
        f32x2 dx = px[j] - c2x;
        f32x2 dy = py[j] - c2y;
        f32x2 dz = pz[j] - c2z;
        f32x2 d = (dx * dx + dy * dy) + dz * dz;
        f32x2 dm = __builtin_elementwise_min(pd[j], d);
        pd[j] = dm;
        if (dm.x > bestv) { bestv = dm.x; besti = 2 * j; }
        if (dm.y > bestv) { bestv = dm.y; besti = 2 * j + 1; }
      }
      float v = bestv;
      DPP_MAX(v, 0x111);
      DPP_MAX(v, 0x112);
      DPP_MAX(v, 0x114);
      DPP_MAX(v, 0x118);
      DPP_MAX(v, 0x142);
      DPP_MAX(v, 0x143);
      float wmax = __int_as_float(__builtin_amdgcn_readlane(__float_as_int(v), 63));
      u64 mask = __ballot(bestv == wmax);
      int owner = __ffsll((long long)mask) - 1;
      int widx = __builtin_amdgcn_readlane(i0 + besti, owner);
      if ((t & 63) == 0)
        swk[(it & 1) * 8 + (t >> 6)] =
            ((u64)__float_as_uint(wmax) << 32) | (unsigned)(4095 - widx);
      __syncthreads();
      // keys read: 4x ds_read_b128 (explicit u64x2) + 3-level tree (r3 lesson:
      // fewer LDS instructions through the shared per-CU pipe)
      const u64x2* kk2 = (const u64x2*)(swk + (it & 1) * 8);
      u64x2 q0 = kk2[0], q1 = kk2[1], q2 = kk2[2], q3 = kk2[3];
      u64 ka = (q0.x > q0.y) ? q0.x : q0.y;
      u64 kb = (q1.x > q1.y) ? q1.x : q1.y;
      u64 kc = (q2.x > q2.y) ? q2.x : q2.y;
      u64 kd = (q3.x > q3.y) ? q3.x : q3.y;
      u64 ke = (ka > kb) ? ka : kb;
      u64 kf2 = (kc > kd) ? kc : kd;
      u64 k0 = (ke > kf2) ? ke : kf2;
      cur = 4095 - (int)(unsigned)(k0 & 0xFFFFFFFFull);
      if (t == 0 && it + 1 < S_) idxs[it + 1] = cur;
    }
    __syncthreads();
    for (int i = t; i < S_; i += 512) {
      float4 v = pts[idxs[i]];
      size_t o = ((size_t)b * S_ + i) * 3;
      new_xyz[o] = v.x; new_xyz[o + 1] = v.y; new_xyz[o + 2] = v.z;
    }
  } else if (blk < 32) {
    int id = (blk - 16) * 512 + t;
    const int st = 16 * 512;
    for (int i = id; i < 32768; i += st) stats[i] = 0.0f;
    for (int i = id; i < 128 * 160; i += st) {
      int n = i / 160, k = i - n * 160;
      float v = (k < 128) ? w0[n * 131 + 3 + k] : (k < 131) ? w0[n * 131 + k - 128] : 0.0f;
      wbf0[i] = f2bf(v);
    }
    for (int i = id; i < 128 * 128; i += st) wbf1[i] = f2bf(w1[i]);
    for (int i = id; i < 256 * 128; i += st) wbf2[i] = f2bf(w2[i]);
  } else {
    float (*tile)[33] = (float(*)[33])smem;
    int blk2 = blk - 32;
    int n0 = (blk2 & 127) * 32;
    int c0 = ((blk2 >> 7) & 3) * 32;
    int b = blk2 >> 9;
    int tx = t & 31, ty = t >> 5;
    #pragma unroll
    for (int j = 0; j < 32; j += 16)
      tile[ty + j][tx] = feat[((size_t)b * 128 + c0 + ty + j) * N_ + n0 + tx];
    __syncthreads();
    #pragma unroll
    for (int j = 0; j < 32; j += 16)
      featT[((size_t)b * N_ + n0 + ty + j) * 128 + c0 + tx] = f2bf(tile[tx][ty + j]);
  }
}

// ---------------- ball query (standalone; bit-exact formula) ----------------
__global__ __launch_bounds__(256) void k_ballq(const float* __restrict__ xyz,
                                               const float* __restrict__ new_xyz,
                                               int* __restrict__ ball_idx) {
  int b = blockIdx.y;
  int s = blockIdx.x * 4 + (threadIdx.x >> 6);
  int lane = threadIdx.x & 63;
  const float* pb = xyz + (size_t)b * N_ * 3;
  size_t q = (size_t)b * S_ + s;
  float qx = new_xyz[q * 3], qy = new_xyz[q * 3 + 1], qz = new_xyz[q * 3 + 2];
  float sq = __fadd_rn(__fadd_rn(__fmul_rn(qx, qx), __fmul_rn(qy, qy)), __fmul_rn(qz, qz));
  int* out = ball_idx + q * K_;
  int total = 0;
  int first_idx = -1;
  for (int basei = 0; basei < N_; basei += 64) {
    int i = basei + lane;
    float fx = pb[i * 3], fy = pb[i * 3 + 1], fz = pb[i * 3 + 2];
    float dot = __fmul_rn(qx, fx);
    dot = __fadd_rn(dot, __fmul_rn(qy, fy));
    dot = __fadd_rn(dot, __fmul_rn(qz, fz));
    float sd = __fadd_rn(__fadd_rn(__fmul_rn(fx, fx), __fmul_rn(fy, fy)), __fmul_rn(fz, fz));
    float dist = __fadd_rn(__fadd_rn(__fmul_rn(-2.0f, dot), sq), sd);
    bool within = (dist <= 0.36f);
    u64 m = __ballot(within);
    if (first_idx < 0 && m) first_idx = basei + __ffsll((long long)m) - 1;
    if (within) {
      int pos = total + __popcll(m & ((1ull << lane) - 1ull));
      if (pos < K_) out[pos] = i;
    }
    total += (int)__popcll(m);
    if (total >= K_) break;
  }
  if (total < K_) {
    int k2 = total + lane;
    if (k2 < K_) out[k2] = first_idx;
  }
}

// ==== MFMA layer kernels — persistent blocks: W/murs staged ONCE, then a
// barrier-free tile loop (A lives in registers since r10) ====
#define MFMA(a, b, c) __builtin_amdgcn_mfma_f32_16x16x32_bf16(a, b, c, 0, 0, 0)
#define NTILES 4096   // 16 batches x 256 s0-tiles

// ---- layer 1: gather(reg) + matmul K=131(pad160)->128 ----
__global__ __launch_bounds__(256) void k_layer1(
    const float* __restrict__ xyz, const float* __restrict__ new_xyz,
    const unsigned short* __restrict__ featT, const int* __restrict__ ball_idx,
    const unsigned short* __restrict__ wbf0, const float* __restrict__ b0,
    unsigned short* __restrict__ y, float* __restrict__ stats) {
  __shared__ __align__(16) unsigned short Wl[128 * PITCH1];   // 42 KB, W only
  __shared__ float sbias[128];
  int t = threadIdx.x;
  int w = t >> 6, L = t & 63, lm = L & 15, lg = L >> 4;
  {
    int n = t >> 1, h = t & 1;
    const uint4* wr = (const uint4*)(wbf0 + n * 160 + h * 80);
    uint4* wl = (uint4*)(Wl + n * PITCH1 + h * 80);
    #pragma unroll
    for (int i = 0; i < 10; ++i) wl[i] = wr[i];
    if (t < 128) sbias[t] = b0[t];
  }
  __syncthreads();

  for (int tile = blockIdx.x; tile < NTILES; tile += gridDim.x) {
    int bb = tile >> 8;
    int s0 = (tile & 255) * 4;
    size_t qg = (size_t)bb * S_ + s0 + w;

    int p0 = ball_idx[qg * K_ + lm];
    int p1 = ball_idx[qg * K_ + 16 + lm];
    const unsigned short* f0 = featT + ((size_t)bb * N_ + p0) * 128;
    const unsigned short* f1 = featT + ((size_t)bb * N_ + p1) * 128;
    bf16x8 a0[5], a1[5];
    #pragma unroll
    for (int kt = 0; kt < 4; ++kt) {
      a0[kt] = *(const bf16x8*)(f0 + kt * 32 + lg * 8);
      a1[kt] = *(const bf16x8*)(f1 + kt * 32 + lg * 8);
    }
    a0[4] = (bf16x8){0, 0, 0, 0, 0, 0, 0, 0};
    a1[4] = (bf16x8){0, 0, 0, 0, 0, 0, 0, 0};
    if (lg == 0) {
      float nx = new_xyz[qg * 3], ny = new_xyz[qg * 3 + 1], nz = new_xyz[qg * 3 + 2];
      const float* pp0 = xyz + ((size_t)bb * N_ + p0) * 3;
      const float* pp1 = xyz + ((size_t)bb * N_ + p1) * 3;
      a0[4][0] = (short)f2bf(pp0[0] - nx);
      a0[4][1] = (short)f2bf(pp0[1] - ny);
      a0[4][2] = (short)f2bf(pp0[2] - nz);
      a1[4][0] = (short)f2bf(pp1[0] - nx);
      a1[4][1] = (short)f2bf(pp1[1] - ny);
      a1[4][2] = (short)f2bf(pp1[2] - nz);
    }
    f32x4 acc[2][8];
    #pragma unroll
    for (int mi = 0; mi < 2; ++mi)
      #pragma unroll
      for (int nt = 0; nt < 8; ++nt) acc[mi][nt] = (f32x4){0.f, 0.f, 0.f, 0.f};
    #pragma unroll
    for (int kt = 0; kt < 5; ++kt) {
      int ko = kt * 32 + lg * 8;
      bf16x8 bv[8];
      #pragma unroll
      for (int nt = 0; nt < 8; ++nt)
        bv[nt] = *(const bf16x8*)&Wl[(nt * 16 + lm) * PITCH1 + ko];
      #pragma unroll
      for (int nt = 0; nt < 8; ++nt) {
        acc[0][nt] = MFMA(a0[kt], bv[nt], acc[0][nt]);
        acc[1][nt] = MFMA(a1[kt], bv[nt], acc[1][nt]);
      }
    }
    int slot = tile & 31;
    #pragma unroll
    for (int nt = 0; nt < 8; ++nt) {
      int col = nt * 16 + lm;
      float bo = sbias[col];
      float s1 = 0.f, s2 = 0.f;
      #pragma unroll
      for (int mi = 0; mi < 2; ++mi)
        #pragma unroll
        for (int r = 0; r < 4; ++r) {
          float yv = acc[mi][nt][r] + bo;
          s1 += yv; s2 += yv * yv;
          int ks = mi * 16 + lg * 4 + r;
          y[(qg * K_ + ks) * 128 + col] = f2bf(yv);
        }
      s1 += __shfl_xor(s1, 16); s2 += __shfl_xor(s2, 16);
      s1 += __shfl_xor(s1, 32); s2 += __shfl_xor(s2, 32);
      if (lg == 0) {
        atomicAdd(stats + ((size_t)slot * 128 + col) * 2, s1);
        atomicAdd(stats + ((size_t)slot * 128 + col) * 2 + 1, s2);
      }
    }
  }
}

// ---- layer 2: murs fold + BN+relu(reg) + matmul 128->128, y IN-PLACE ----
__global__ __launch_bounds__(256) void k_layer2(
    unsigned short* y, const float* __restrict__ stats,
    const float* __restrict__ gamma, const float* __restrict__ beta,
    const unsigned short* __restrict__ wbf1, const float* __restrict__ b1,
    float* __restrict__ stats2) {
  __shared__ __align__(16) unsigned short Wl[128 * PITCH2];   // 34 KB, W only
  __shared__ __align__(16) float sa[128], sd[128];
  __shared__ float sbias[128];
  int t = threadIdx.x;
  int w = t >> 6, L = t & 63, lm = L & 15, lg = L >> 4;
  if (t < 128) {
    float s1 = 0.0f, s2 = 0.0f;
    for (int sl = 0; sl < 32; ++sl) {
      s1 += stats[((size_t)sl * 128 + t) * 2];
      s2 += stats[((size_t)sl * 128 + t) * 2 + 1];
    }
    const float inv = 1.0f / 524288.0f;
    float mu = s1 * inv;
    float var = s2 * inv - mu * mu;
    float a = gamma[t] * rsqrtf(var + 1e-5f);
    sa[t] = a;
    sd[t] = beta[t] - a * mu;
    sbias[t] = b1[t];
  }
  {
    int n = t >> 1, h = t & 1;
    const uint4* wr = (const uint4*)(wbf1 + n * 128 + h * 64);
    uint4* wl = (uint4*)(Wl + n * PITCH2 + h * 64);
    #pragma unroll
    for (int i = 0; i < 8; ++i) wl[i] = wr[i];
  }
  __syncthreads();

  for (int tile = blockIdx.x; tile < NTILES; tile += gridDim.x) {
    int bb = tile >> 8;
    int s0 = (tile & 255) * 4;
    size_t qg = (size_t)bb * S_ + s0 + w;

    const u16x8* yr0 = (const u16x8*)(y + (qg * K_ + lm) * 128);
    const u16x8* yr1 = (const u16x8*)(y + (qg * K_ + 16 + lm) * 128);
    u16x8 raw0[4], raw1[4];
    #pragma unroll
    for (int kt = 0; kt < 4; ++kt) { raw0[kt] = yr0[kt * 4 + lg]; raw1[kt] = yr1[kt * 4 + lg]; }
    bf16x8 a0[4], a1[4];
    #pragma unroll
    for (int kt = 0; kt < 4; ++kt) {
      int c = kt * 32 + lg * 8;
      f32x4 A0 = *(const f32x4*)&sa[c], A1 = *(const f32x4*)&sa[c + 4];
      f32x4 D0 = *(const f32x4*)&sd[c], D1 = *(const f32x4*)&sd[c + 4];
      #pragma unroll
      for (int j = 0; j < 4; ++j) {
        a0[kt][j]     = (short)f2bf(fmaxf(A0[j] * bf2f(raw0[kt][j])     + D0[j], 0.f));
        a0[kt][j + 4] = (short)f2bf(fmaxf(A1[j] * bf2f(raw0[kt][j + 4]) + D1[j], 0.f));
        a1[kt][j]     = (short)f2bf(fmaxf(A0[j] * bf2f(raw1[kt][j])     + D0[j], 0.f));
        a1[kt][j + 4] = (short)f2bf(fmaxf(A1[j] * bf2f(raw1[kt][j + 4]) + D1[j], 0.f));
      }
    }
    f32x4 acc[2][8];
    #pragma unroll
    for (int mi = 0; mi < 2; ++mi)
      #pragma unroll
      for (int nt = 0; nt < 8; ++nt) acc[mi][nt] = (f32x4){0.f, 0.f, 0.f, 0.f};
    #pragma unroll
    for (int kt = 0; kt < 4; ++kt) {
      int ko = kt * 32 + lg * 8;
      bf16x8 bv[8];
      #pragma unroll
      for (int nt = 0; nt < 8; ++nt)
        bv[nt] = *(const bf16x8*)&Wl[(nt * 16 + lm) * PITCH2 + ko];
      #pragma unroll
      for (int nt = 0; nt < 8; ++nt) {
        acc[0][nt] = MFMA(a0[kt], bv[nt], acc[0][nt]);
        acc[1][nt] = MFMA(a1[kt], bv[nt], acc[1][nt]);
      }
    }
    int slot = tile & 31;
    #pragma unroll
    for (int nt = 0; nt < 8; ++nt) {
      int col = nt * 16 + lm;
      float bo = sbias[col];
      float s1 = 0.f, s2 = 0.f;
      #pragma unroll
      for (int mi = 0; mi < 2; ++mi)
        #pragma unroll
        for (int r = 0; r < 4; ++r) {
          float yv = acc[mi][nt][r] + bo;
          s1 += yv; s2 += yv * yv;
          int ks = mi * 16 + lg * 4 + r;
          y[(qg * K_ + ks) * 128 + col] = f2bf(yv);
        }
      s1 += __shfl_xor(s1, 16); s2 += __shfl_xor(s2, 16);
      s1 += __shfl_xor(s1, 32); s2 += __shfl_xor(s2, 32);
      if (lg == 0) {
        atomicAdd(stats2 + ((size_t)slot * 128 + col) * 2, s1);
        atomicAdd(stats2 + ((size_t)slot * 128 + col) * 2 + 1, s2);
      }
    }
  }
}

// ---- layer 3: murs fold + BN+relu(reg) + matmul 128->256 (nh per block.y) ----
__global__ __launch_bounds__(256) void k_layer3(
    const unsigned short* __restrict__ y, const float* __restrict__ stats2,
    const float* __restrict__ gamma, const float* __restrict__ beta,
    const unsigned short* __restrict__ wbf2, const float* __restrict__ b2,
    unsigned short* __restrict__ ymax, unsigned short* __restrict__ ymin,
    float* __restrict__ stats3) {
  __shared__ __align__(16) unsigned short Wl[128 * PITCH2];
  __shared__ __align__(16) float sa[128], sd[128];
  __shared__ float sbias[128];
  int nh = blockIdx.y, t = threadIdx.x;
  int w = t >> 6, L = t & 63, lm = L & 15, lg = L >> 4;
  if (t < 128) {
    float s1 = 0.0f, s2 = 0.0f;
    for (int sl = 0; sl < 32; ++sl) {
      s1 += stats2[((size_t)sl * 128 + t) * 2];
      s2 += stats2[((size_t)sl * 128 + t) * 2 + 1];
    }
    const float inv = 1.0f / 524288.0f;
    float mu = s1 * inv;
    float var = s2 * inv - mu * mu;
    float a = gamma[t] * rsqrtf(var + 1e-5f);
    sa[t] = a;
    sd[t] = beta[t] - a * mu;
    sbias[t] = b2[nh * 128 + t];
  }
  {
    int n = t >> 1, h = t & 1;
    const uint4* wr = (const uint4*)(wbf2 + (size_t)(nh * 128 + n) * 128 + h * 64);
    uint4* wl = (uint4*)(Wl + n * PITCH2 + h * 64);
    #pragma unroll
    for (int i = 0; i < 8; ++i) wl[i] = wr[i];
  }
  __syncthreads();

  for (int tile = blockIdx.x; tile < NTILES; tile += gridDim.x) {
    int bb = tile >> 8;
    int s0 = (tile & 255) * 4;
    size_t qg = (size_t)bb * S_ + s0 + w;

    const u16x8* yr0 = (const u16x8*)(y + (qg * K_ + lm) * 128);
    const u16x8* yr1 = (const u16x8*)(y + (qg * K_ + 16 + lm) * 128);
    u16x8 raw0[4], raw1[4];
    #pragma unroll
    for (int kt = 0; kt < 4; ++kt) { raw0[kt] = yr0[kt * 4 + lg]; raw1[kt] = yr1[kt * 4 + lg]; }
    bf16x8 a0[4], a1[4];
    #pragma unroll
    for (int kt = 0; kt < 4; ++kt) {
      int c = kt * 32 + lg * 8;
      f32x4 A0 = *(const f32x4*)&sa[c], A1 = *(const f32x4*)&sa[c + 4];
      f32x4 D0 = *(const f32x4*)&sd[c], D1 = *(const f32x4*)&sd[c + 4];
      #pragma unroll
      for (int j = 0; j < 4; ++j) {
        a0[kt][j]     = (short)f2bf(fmaxf(A0[j] * bf2f(raw0[kt][j])     + D0[j], 0.f));
        a0[kt][j + 4] = (short)f2bf(fmaxf(A1[j] * bf2f(raw0[kt][j + 4]) + D1[j], 0.f));
        a1[kt][j]     = (short)f2bf(fmaxf(A0[j] * bf2f(raw1[kt][j])     + D0[j], 0.f));
        a1[kt][j + 4] = (short)f2bf(fmaxf(A1[j] * bf2f(raw1[kt][j + 4]) + D1[j], 0.f));
      }
    }
    f32x4 acc[2][8];
    #pragma unroll
    for (int mi = 0; mi < 2; ++mi)
      #pragma unroll
      for (int nt = 0; nt < 8; ++nt) acc[mi][nt] = (f32x4){0.f, 0.f, 0.f, 0.f};
    #pragma unroll
    for (int kt = 0; kt < 4; ++kt) {
      int ko = kt * 32 + lg * 8;
      bf16x8 bv[8];
      #pragma unroll
      for (int nt = 0; nt < 8; ++nt)
        bv[nt] = *(const bf16x8*)&Wl[(nt * 16 + lm) * PITCH2 + ko];
      #pragma unroll
      for (int nt = 0; nt < 8; ++nt) {
        acc[0][nt] = MFMA(a0[kt], bv[nt], acc[0][nt]);
        acc[1][nt] = MFMA(a1[kt], bv[nt], acc[1][nt]);
      }
    }
    int slot = tile & 31;
    #pragma unroll
    for (int nt = 0; nt < 8; ++nt) {
      int col = nt * 16 + lm;
      int o = nh * 128 + col;
      float bo = sbias[col];
      float s1 = 0.f, s2 = 0.f, mx = -3.4e38f, mn = 3.4e38f;
      #pragma unroll
      for (int mi = 0; mi < 2; ++mi)
        #pragma unroll
        for (int r = 0; r < 4; ++r) {
          float yv = acc[mi][nt][r] + bo;
          s1 += yv; s2 += yv * yv;
          mx = fmaxf(mx, yv); mn = fminf(mn, yv);
        }
      s1 += __shfl_xor(s1, 16); s2 += __shfl_xor(s2, 16);
      s1 += __shfl_xor(s1, 32); s2 += __shfl_xor(s2, 32);
      mx = fmaxf(mx, __shfl_xor(mx, 16)); mx = fmaxf(mx, __shfl_xor(mx, 32));
      mn = fminf(mn, __shfl_xor(mn, 16)); mn = fminf(mn, __shfl_xor(mn, 32));
      if (lg == 0) {
        ymax[qg * 256 + o] = f2bf(mx);
        ymin[qg * 256 + o] = f2bf(mn);
        atomicAdd(stats3 + ((size_t)slot * 256 + o) * 2, s1);
        atomicAdd(stats3 + ((size_t)slot * 256 + o) * 2 + 1, s2);
      }
    }
  }
}

// -------- final: murs fold + select extreme by sign(a) + BN+relu + transpose --------
__global__ __launch_bounds__(256) void k_final(const unsigned short* __restrict__ ymax,
                                               const unsigned short* __restrict__ ymin,
                                               const float* __restrict__ stats3,
                                               const float* __restrict__ gamma,
                                               const float* __restrict__ beta,
                                               float* __restrict__ out2) {
  __shared__ float tile[32][33];
  __shared__ float smA[32], smD[32];
  int b = blockIdx.z, o0 = blockIdx.y * 32, s0 = blockIdx.x * 32;
  int tx = threadIdx.x, ty = threadIdx.y;
  if (ty == 0) {
    int c = o0 + tx;
    float s1 = 0.0f, s2 = 0.0f;
    for (int sl = 0; sl < 32; ++sl) {
      s1 += stats3[((size_t)sl * 256 + c) * 2];
      s2 += stats3[((size_t)sl * 256 + c) * 2 + 1];
    }
    const float inv = 1.0f / 524288.0f;
    float mu = s1 * inv;
    float var = s2 * inv - mu * mu;
    float a = gamma[c] * rsqrtf(var + 1e-5f);
    smA[tx] = a;
    smD[tx] = beta[c] - a * mu;
  }
  __syncthreads();
  float a_rd = smA[tx];
  #pragma unroll
  for (int j = 0; j < 32; j += 8) {
    size_t src = ((size_t)b * S_ + s0 + ty + j) * 256 + o0 + tx;
    tile[ty + j][tx] = (a_rd >= 0.0f) ? bf2f(ymax[src]) : bf2f(ymin[src]);
  }
  __syncthreads();
  #pragma unroll
  for (int j = 0; j < 32; j += 8) {
    float a = smA[ty + j], dd = smD[ty + j];
    out2[((size_t)b * 256 + o0 + ty + j) * S_ + s0 + tx] = fmaxf(a * tile[tx][ty + j] + dd, 0.0f);
  }
}

extern "C" void kernel_launch(void* const* d_in, const int* in_sizes, int n_in,
                              void* d_out, int out_size, void* d_ws, size_t ws_size,
                              hipStream_t stream) {
  (void)in_sizes; (void)n_in; (void)out_size; (void)ws_size;
  const float* xyz  = (const float*)d_in[0];
  const float* feat = (const float*)d_in[1];
  const float* w0   = (const float*)d_in[2];
  const float* b0   = (const float*)d_in[3];
  const float* ga0  = (const float*)d_in[4];
  const float* be0  = (const float*)d_in[5];
  const float* w1   = (const float*)d_in[6];
  const float* b1   = (const float*)d_in[7];
  const float* ga1  = (const float*)d_in[8];
  const float* be1  = (const float*)d_in[9];
  const float* w2   = (const float*)d_in[10];
  const float* b2   = (const float*)d_in[11];
  const float* ga2  = (const float*)d_in[12];
  const float* be2  = (const float*)d_in[13];

  float* out_xyz  = (float*)d_out;
  float* out_feat = out_xyz + (size_t)B_ * S_ * 3;

  char* ws = (char*)d_ws;
  size_t off = 0;
  auto alloc = [&](size_t bytes) -> void* {
    void* p = ws + off;
    off += (bytes + 255) & ~(size_t)255;
    return p;
  };
  unsigned short* featT = (unsigned short*)alloc((size_t)B_ * N_ * 128 * 2);  // 16.8 MB bf16
  int*   ball  = (int*)alloc((size_t)B_ * S_ * K_ * 4);                       // 2.1 MB
  float* stats = (float*)alloc(32768 * 4);
  unsigned short* wbf0 = (unsigned short*)alloc(128 * 160 * 2);
  unsigned short* wbf1 = (unsigned short*)alloc(128 * 128 * 2);
  unsigned short* wbf2 = (unsigned short*)alloc(256 * 128 * 2);
  unsigned short* ymaxb = (unsigned short*)alloc((size_t)B_ * S_ * 256 * 2);  // 8.4 MB
  unsigned short* yminb = (unsigned short*)alloc((size_t)B_ * S_ * 256 * 2);  // 8.4 MB
  unsigned short* y = (unsigned short*)alloc((size_t)B_ * S_ * K_ * 128 * 2); // 134 MB

  // blocks: 16 fps | 16 init | 8192 transpose
  k_front<<<16 + 16 + 8192, 512, 0, stream>>>(xyz, out_xyz, feat, featT,
                                              w0, w1, w2, wbf0, wbf1, wbf2, stats);
  k_ballq<<<dim3(256, 16), 256, 0, stream>>>(xyz, out_xyz, ball);
  // persistent grids: layer1 3 blocks/CU (43KB LDS), layer2 4/CU, layer3 (512,2)
  k_layer1<<<768, 256, 0, stream>>>(xyz, out_xyz, featT, ball, wbf0, b0, y, stats);
  k_layer2<<<1024, 256, 0, stream>>>(y, stats, ga0, be0, wbf1, b1, stats + 8192);
  k_layer3<<<dim3(512, 2), 256, 0, stream>>>(y, stats + 8192, ga1, be1, wbf2, b2,
                                             ymaxb, yminb, stats + 16384);
  k_final<<<dim3(32, 8, 16), dim3(32, 8), 0, stream>>>(ymaxb, yminb, stats + 16384,
                                                       ga2, be2, out_feat);
}

// Round 5
// 1022.320 us; speedup vs baseline: 1.4328x; 1.0615x over previous
//
#include <hip/hip_runtime.h>

#define B_ 16
#define N_ 4096
#define S_ 1024
#define K_ 32
#define PITCH2 136   // 128 + 8 shorts: b128 frag reads -> 2-way bank alias (free)
#define PITCH1 168   // 160 + 8 shorts

typedef unsigned long long u64;
typedef short bf16x8 __attribute__((ext_vector_type(8)));
typedef unsigned short u16x8 __attribute__((ext_vector_type(8)));
typedef float f32x4 __attribute__((ext_vector_type(4)));
typedef float f32x2 __attribute__((ext_vector_type(2)));

__device__ __forceinline__ unsigned short f2bf(float f) {
  unsigned u = __float_as_uint(f);
  unsigned r = (u + 0x7FFFu + ((u >> 16) & 1u)) >> 16;
  return (unsigned short)r;
}
__device__ __forceinline__ float bf2f(unsigned short h) {
  return __uint_as_float(((unsigned)h) << 16);
}

// DPP wave64 max reduce: shr1,2,4,8 + bcast15 + bcast31 -> lane 63 = wave max
#define DPP_MAX(v, ctrl)                                                        \
  {                                                                             \
    int _t = __builtin_amdgcn_update_dpp(__float_as_int(v), __float_as_int(v),  \
                                         ctrl, 0xf, 0xf, false);                \
    v = fmaxf(v, __int_as_float(_t));                                           \
  }

// ===== fused front kernel: blocks 0-15 FPS | 16-31 init | 32+ transpose =====
// FPS: proven R0 structure (8 waves x 8 pts/lane, serial argmax, one barrier).
// R5 change: cross-wave key exchange via ONE ds_max_u64 per wave + one uniform
// b64 read, replacing 8 writes + 32 b128 reads (LDS instrs/CU/iter 49 -> 26).
// Slot reuse is race-free via 3-slot rotation: slot j%3 is atomic'd at iter j,
// read at tail j, reset at tail j+1 (== (s+2)%3 of that tail); barriers j-2 /
// j-1 order reads-before-reset and reset-before-next-atomic respectively.
__global__ __launch_bounds__(512) void k_front(
    const float* __restrict__ xyz, float* __restrict__ new_xyz,
    const float* __restrict__ feat, unsigned short* __restrict__ featT,
    const float* __restrict__ w0, const float* __restrict__ w1,
    const float* __restrict__ w2, unsigned short* __restrict__ wbf0,
    unsigned short* __restrict__ wbf1, unsigned short* __restrict__ wbf2,
    float* __restrict__ stats) {
  __shared__ __align__(16) float smem[N_ * 4 + S_ + 64];
  int blk = blockIdx.x, t = threadIdx.x;

  if (blk < 16) {
#pragma clang fp contract(off)
#if __has_builtin(__builtin_amdgcn_s_setprio)
    __builtin_amdgcn_s_setprio(3);
#endif
    float4* pts = (float4*)smem;
    int* idxs = (int*)(smem + N_ * 4);
    u64* km = (u64*)(smem + N_ * 4 + S_);   // 3 rotating max-key slots
    int b = blk;
    const float* base = xyz + (size_t)b * N_ * 3;
    for (int i = t; i < N_; i += 512)
      pts[i] = make_float4(base[i * 3], base[i * 3 + 1], base[i * 3 + 2], 0.0f);
    if (t == 0) { idxs[0] = 0; km[0] = 0; km[1] = 0; km[2] = 0; }
    __syncthreads();
    f32x2 px[4], py[4], pz[4], pd[4];
    int i0 = t * 8;
    #pragma unroll
    for (int j = 0; j < 4; ++j) {
      float4 p0 = pts[i0 + 2 * j], p1 = pts[i0 + 2 * j + 1];
      px[j] = (f32x2){p0.x, p1.x};
      py[j] = (f32x2){p0.y, p1.y};
      pz[j] = (f32x2){p0.z, p1.z};
      pd[j] = (f32x2){1e10f, 1e10f};
    }
    int cur = 0;
    int sl = 0;
    for (int it = 0; it < S_; ++it) {
      float4 c = pts[cur];
      f32x2 c2x = (f32x2){c.x, c.x}, c2y = (f32x2){c.y, c.y}, c2z = (f32x2){c.z, c.z};
      float bestv = -1.0f; int besti = 0;
      #pragma unroll
      for (int j = 0; j < 4; ++j) {
        f32x2 dx = px[j] - c2x;
        f32x2 dy = py[j] - c2y;
        f32x2 dz = pz[j] - c2z;
        f32x2 d = (dx * dx + dy * dy) + dz * dz;
        f32x2 dm = __builtin_elementwise_min(pd[j], d);
        pd[j] = dm;
        if (dm.x > bestv) { bestv = dm.x; besti = 2 * j; }
        if (dm.y > bestv) { bestv = dm.y; besti = 2 * j + 1; }
      }
      float v = bestv;
      DPP_MAX(v, 0x111);
      DPP_MAX(v, 0x112);
      DPP_MAX(v, 0x114);
      DPP_MAX(v, 0x118);
      DPP_MAX(v, 0x142);
      DPP_MAX(v, 0x143);
      float wmax = __int_as_float(__builtin_amdgcn_readlane(__float_as_int(v), 63));
      u64 mask = __ballot(bestv == wmax);
      int owner = __ffsll((long long)mask) - 1;
      int widx = __builtin_amdgcn_readlane(i0 + besti, owner);
      if ((t & 63) == 0)
        atomicMax((unsigned long long*)&km[sl],
                  ((u64)__float_as_uint(wmax) << 32) | (unsigned)(4095 - widx));
      __syncthreads();
      u64 k0 = km[sl];   // uniform-address broadcast read
      cur = 4095 - (int)(unsigned)(k0 & 0xFFFFFFFFull);
      if (t == 0) {
        if (it + 1 < S_) idxs[it + 1] = cur;
        km[sl == 0 ? 2 : sl - 1] = 0;   // reset slot (sl+2)%3 for iter it+2
      }
      sl = (sl == 2) ? 0 : sl + 1;
    }
    __syncthreads();
    for (int i = t; i < S_; i += 512) {
      float4 v = pts[idxs[i]];
      size_t o = ((size_t)b * S_ + i) * 3;
      new_xyz[o] = v.x; new_xyz[o + 1] = v.y; new_xyz[o + 2] = v.z;
    }
  } else if (blk < 32) {
    int id = (blk - 16) * 512 + t;
    const int st = 16 * 512;
    for (int i = id; i < 32768; i += st) stats[i] = 0.0f;
    for (int i = id; i < 128 * 160; i += st) {
      int n = i / 160, k = i - n * 160;
      float v = (k < 128) ? w0[n * 131 + 3 + k] : (k < 131) ? w0[n * 131 + k - 128] : 0.0f;
      wbf0[i] = f2bf(v);
    }
    for (int i = id; i < 128 * 128; i += st) wbf1[i] = f2bf(w1[i]);
    for (int i = id; i < 256 * 128; i += st) wbf2[i] = f2bf(w2[i]);
  } else {
    float (*tile)[33] = (float(*)[33])smem;
    int blk2 = blk - 32;
    int n0 = (blk2 & 127) * 32;
    int c0 = ((blk2 >> 7) & 3) * 32;
    int b = blk2 >> 9;
    int tx = t & 31, ty = t >> 5;
    #pragma unroll
    for (int j = 0; j < 32; j += 16)
      tile[ty + j][tx] = feat[((size_t)b * 128 + c0 + ty + j) * N_ + n0 + tx];
    __syncthreads();
    #pragma unroll
    for (int j = 0; j < 32; j += 16)
      featT[((size_t)b * N_ + n0 + ty + j) * 128 + c0 + tx] = f2bf(tile[tx][ty + j]);
  }
}

// ---------------- ball query (standalone; bit-exact formula) ----------------
__global__ __launch_bounds__(256) void k_ballq(const float* __restrict__ xyz,
                                               const float* __restrict__ new_xyz,
                                               int* __restrict__ ball_idx) {
  int b = blockIdx.y;
  int s = blockIdx.x * 4 + (threadIdx.x >> 6);
  int lane = threadIdx.x & 63;
  const float* pb = xyz + (size_t)b * N_ * 3;
  size_t q = (size_t)b * S_ + s;
  float qx = new_xyz[q * 3], qy = new_xyz[q * 3 + 1], qz = new_xyz[q * 3 + 2];
  float sq = __fadd_rn(__fadd_rn(__fmul_rn(qx, qx), __fmul_rn(qy, qy)), __fmul_rn(qz, qz));
  int* out = ball_idx + q * K_;
  int total = 0;
  int first_idx = -1;
  for (int basei = 0; basei < N_; basei += 64) {
    int i = basei + lane;
    float fx = pb[i * 3], fy = pb[i * 3 + 1], fz = pb[i * 3 + 2];
    float dot = __fmul_rn(qx, fx);
    dot = __fadd_rn(dot, __fmul_rn(qy, fy));
    dot = __fadd_rn(dot, __fmul_rn(qz, fz));
    float sd = __fadd_rn(__fadd_rn(__fmul_rn(fx, fx), __fmul_rn(fy, fy)), __fmul_rn(fz, fz));
    float dist = __fadd_rn(__fadd_rn(__fmul_rn(-2.0f, dot), sq), sd);
    bool within = (dist <= 0.36f);
    u64 m = __ballot(within);
    if (first_idx < 0 && m) first_idx = basei + __ffsll((long long)m) - 1;
    if (within) {
      int pos = total + __popcll(m & ((1ull << lane) - 1ull));
      if (pos < K_) out[pos] = i;
    }
    total += (int)__popcll(m);
    if (total >= K_) break;
  }
  if (total < K_) {
    int k2 = total + lane;
    if (k2 < K_) out[k2] = first_idx;
  }
}

// ==== MFMA layer kernels — persistent blocks: W/murs staged ONCE, then a
// barrier-free tile loop (A lives in registers since r10) ====
#define MFMA(a, b, c) __builtin_amdgcn_mfma_f32_16x16x32_bf16(a, b, c, 0, 0, 0)
#define NTILES 4096   // 16 batches x 256 s0-tiles

// ---- layer 1: gather(reg) + matmul K=131(pad160)->128 ----
__global__ __launch_bounds__(256) void k_layer1(
    const float* __restrict__ xyz, const float* __restrict__ new_xyz,
    const unsigned short* __restrict__ featT, const int* __restrict__ ball_idx,
    const unsigned short* __restrict__ wbf0, const float* __restrict__ b0,
    unsigned short* __restrict__ y, float* __restrict__ stats) {
  __shared__ __align__(16) unsigned short Wl[128 * PITCH1];   // 42 KB, W only
  __shared__ float sbias[128];
  int t = threadIdx.x;
  int w = t >> 6, L = t & 63, lm = L & 15, lg = L >> 4;
  {
    int n = t >> 1, h = t & 1;
    const uint4* wr = (const uint4*)(wbf0 + n * 160 + h * 80);
    uint4* wl = (uint4*)(Wl + n * PITCH1 + h * 80);
    #pragma unroll
    for (int i = 0; i < 10; ++i) wl[i] = wr[i];
    if (t < 128) sbias[t] = b0[t];
  }
  __syncthreads();

  for (int tile = blockIdx.x; tile < NTILES; tile += gridDim.x) {
    int bb = tile >> 8;
    int s0 = (tile & 255) * 4;
    size_t qg = (size_t)bb * S_ + s0 + w;

    int p0 = ball_idx[qg * K_ + lm];
    int p1 = ball_idx[qg * K_ + 16 + lm];
    const unsigned short* f0 = featT + ((size_t)bb * N_ + p0) * 128;
    const unsigned short* f1 = featT + ((size_t)bb * N_ + p1) * 128;
    bf16x8 a0[5], a1[5];
    #pragma unroll
    for (int kt = 0; kt < 4; ++kt) {
      a0[kt] = *(const bf16x8*)(f0 + kt * 32 + lg * 8);
      a1[kt] = *(const bf16x8*)(f1 + kt * 32 + lg * 8);
    }
    a0[4] = (bf16x8){0, 0, 0, 0, 0, 0, 0, 0};
    a1[4] = (bf16x8){0, 0, 0, 0, 0, 0, 0, 0};
    if (lg == 0) {
      float nx = new_xyz[qg * 3], ny = new_xyz[qg * 3 + 1], nz = new_xyz[qg * 3 + 2];
      const float* pp0 = xyz + ((size_t)bb * N_ + p0) * 3;
      const float* pp1 = xyz + ((size_t)bb * N_ + p1) * 3;
      a0[4][0] = (short)f2bf(pp0[0] - nx);
      a0[4][1] = (short)f2bf(pp0[1] - ny);
      a0[4][2] = (short)f2bf(pp0[2] - nz);
      a1[4][0] = (short)f2bf(pp1[0] - nx);
      a1[4][1] = (short)f2bf(pp1[1] - ny);
      a1[4][2] = (short)f2bf(pp1[2] - nz);
    }
    f32x4 acc[2][8];
    #pragma unroll
    for (int mi = 0; mi < 2; ++mi)
      #pragma unroll
      for (int nt = 0; nt < 8; ++nt) acc[mi][nt] = (f32x4){0.f, 0.f, 0.f, 0.f};
    #pragma unroll
    for (int kt = 0; kt < 5; ++kt) {
      int ko = kt * 32 + lg * 8;
      bf16x8 bv[8];
      #pragma unroll
      for (int nt = 0; nt < 8; ++nt)
        bv[nt] = *(const bf16x8*)&Wl[(nt * 16 + lm) * PITCH1 + ko];
      #pragma unroll
      for (int nt = 0; nt < 8; ++nt) {
        acc[0][nt] = MFMA(a0[kt], bv[nt], acc[0][nt]);
        acc[1][nt] = MFMA(a1[kt], bv[nt], acc[1][nt]);
      }
    }
    int slot = tile & 31;
    #pragma unroll
    for (int nt = 0; nt < 8; ++nt) {
      int col = nt * 16 + lm;
      float bo = sbias[col];
      float s1 = 0.f, s2 = 0.f;
      #pragma unroll
      for (int mi = 0; mi < 2; ++mi)
        #pragma unroll
        for (int r = 0; r < 4; ++r) {
          float yv = acc[mi][nt][r] + bo;
          s1 += yv; s2 += yv * yv;
          int ks = mi * 16 + lg * 4 + r;
          y[(qg * K_ + ks) * 128 + col] = f2bf(yv);
        }
      s1 += __shfl_xor(s1, 16); s2 += __shfl_xor(s2, 16);
      s1 += __shfl_xor(s1, 32); s2 += __shfl_xor(s2, 32);
      if (lg == 0) {
        atomicAdd(stats + ((size_t)slot * 128 + col) * 2, s1);
        atomicAdd(stats + ((size_t)slot * 128 + col) * 2 + 1, s2);
      }
    }
  }
}

// ---- layer 2: murs fold + BN+relu(reg) + matmul 128->128, y IN-PLACE ----
__global__ __launch_bounds__(256) void k_layer2(
    unsigned short* y, const float* __restrict__ stats,
    const float* __restrict__ gamma, const float* __restrict__ beta,
    const unsigned short* __restrict__ wbf1, const float* __restrict__ b1,
    float* __restrict__ stats2) {
  __shared__ __align__(16) unsigned short Wl[128 * PITCH2];   // 34 KB, W only
  __shared__ __align__(16) float sa[128], sd[128];
  __shared__ float sbias[128];
  int t = threadIdx.x;
  int w = t >> 6, L = t & 63, lm = L & 15, lg = L >> 4;
  if (t < 128) {
    float s1 = 0.0f, s2 = 0.0f;
    for (int sl = 0; sl < 32; ++sl) {
      s1 += stats[((size_t)sl * 128 + t) * 2];
      s2 += stats[((size_t)sl * 128 + t) * 2 + 1];
    }
    const float inv = 1.0f / 524288.0f;
    float mu = s1 * inv;
    float var = s2 * inv - mu * mu;
    float a = gamma[t] * rsqrtf(var + 1e-5f);
    sa[t] = a;
    sd[t] = beta[t] - a * mu;
    sbias[t] = b1[t];
  }
  {
    int n = t >> 1, h = t & 1;
    const uint4* wr = (const uint4*)(wbf1 + n * 128 + h * 64);
    uint4* wl = (uint4*)(Wl + n * PITCH2 + h * 64);
    #pragma unroll
    for (int i = 0; i < 8; ++i) wl[i] = wr[i];
  }
  __syncthreads();

  for (int tile = blockIdx.x; tile < NTILES; tile += gridDim.x) {
    int bb = tile >> 8;
    int s0 = (tile & 255) * 4;
    size_t qg = (size_t)bb * S_ + s0 + w;

    const u16x8* yr0 = (const u16x8*)(y + (qg * K_ + lm) * 128);
    const u16x8* yr1 = (const u16x8*)(y + (qg * K_ + 16 + lm) * 128);
    u16x8 raw0[4], raw1[4];
    #pragma unroll
    for (int kt = 0; kt < 4; ++kt) { raw0[kt] = yr0[kt * 4 + lg]; raw1[kt] = yr1[kt * 4 + lg]; }
    bf16x8 a0[4], a1[4];
    #pragma unroll
    for (int kt = 0; kt < 4; ++kt) {
      int c = kt * 32 + lg * 8;
      f32x4 A0 = *(const f32x4*)&sa[c], A1 = *(const f32x4*)&sa[c + 4];
      f32x4 D0 = *(const f32x4*)&sd[c], D1 = *(const f32x4*)&sd[c + 4];
      #pragma unroll
      for (int j = 0; j < 4; ++j) {
        a0[kt][j]     = (short)f2bf(fmaxf(A0[j] * bf2f(raw0[kt][j])     + D0[j], 0.f));
        a0[kt][j + 4] = (short)f2bf(fmaxf(A1[j] * bf2f(raw0[kt][j + 4]) + D1[j], 0.f));
        a1[kt][j]     = (short)f2bf(fmaxf(A0[j] * bf2f(raw1[kt][j])     + D0[j], 0.f));
        a1[kt][j + 4] = (short)f2bf(fmaxf(A1[j] * bf2f(raw1[kt][j + 4]) + D1[j], 0.f));
      }
    }
    f32x4 acc[2][8];
    #pragma unroll
    for (int mi = 0; mi < 2; ++mi)
      #pragma unroll
      for (int nt = 0; nt < 8; ++nt) acc[mi][nt] = (f32x4){0.f, 0.f, 0.f, 0.f};
    #pragma unroll
    for (int kt = 0; kt < 4; ++kt) {
      int ko = kt * 32 + lg * 8;
      bf16x8 bv[8];
      #pragma unroll
      for (int nt = 0; nt < 8; ++nt)
        bv[nt] = *(const bf16x8*)&Wl[(nt * 16 + lm) * PITCH2 + ko];
      #pragma unroll
      for (int nt = 0; nt < 8; ++nt) {
        acc[0][nt] = MFMA(a0[kt], bv[nt], acc[0][nt]);
        acc[1][nt] = MFMA(a1[kt], bv[nt], acc[1][nt]);
      }
    }
    int slot = tile & 31;
    #pragma unroll
    for (int nt = 0; nt < 8; ++nt) {
      int col = nt * 16 + lm;
      float bo = sbias[col];
      float s1 = 0.f, s2 = 0.f;
      #pragma unroll
      for (int mi = 0; mi < 2; ++mi)
        #pragma unroll
        for (int r = 0; r < 4; ++r) {
          float yv = acc[mi][nt][r] + bo;
          s1 += yv; s2 += yv * yv;
          int ks = mi * 16 + lg * 4 + r;
          y[(qg * K_ + ks) * 128 + col] = f2bf(yv);
        }
      s1 += __shfl_xor(s1, 16); s2 += __shfl_xor(s2, 16);
      s1 += __shfl_xor(s1, 32); s2 += __shfl_xor(s2, 32);
      if (lg == 0) {
        atomicAdd(stats2 + ((size_t)slot * 128 + col) * 2, s1);
        atomicAdd(stats2 + ((size_t)slot * 128 + col) * 2 + 1, s2);
      }
    }
  }
}

// ---- layer 3: murs fold + BN+relu(reg) + matmul 128->256 (nh per block.y) ----
__global__ __launch_bounds__(256) void k_layer3(
    const unsigned short* __restrict__ y, const float* __restrict__ stats2,
    const float* __restrict__ gamma, const float* __restrict__ beta,
    const unsigned short* __restrict__ wbf2, const float* __restrict__ b2,
    unsigned short* __restrict__ ymax, unsigned short* __restrict__ ymin,
    float* __restrict__ stats3) {
  __shared__ __align__(16) unsigned short Wl[128 * PITCH2];
  __shared__ __align__(16) float sa[128], sd[128];
  __shared__ float sbias[128];
  int nh = blockIdx.y, t = threadIdx.x;
  int w = t >> 6, L = t & 63, lm = L & 15, lg = L >> 4;
  if (t < 128) {
    float s1 = 0.0f, s2 = 0.0f;
    for (int sl = 0; sl < 32; ++sl) {
      s1 += stats2[((size_t)sl * 128 + t) * 2];
      s2 += stats2[((size_t)sl * 128 + t) * 2 + 1];
    }
    const float inv = 1.0f / 524288.0f;
    float mu = s1 * inv;
    float var = s2 * inv - mu * mu;
    float a = gamma[t] * rsqrtf(var + 1e-5f);
    sa[t] = a;
    sd[t] = beta[t] - a * mu;
    sbias[t] = b2[nh * 128 + t];
  }
  {
    int n = t >> 1, h = t & 1;
    const uint4* wr = (const uint4*)(wbf2 + (size_t)(nh * 128 + n) * 128 + h * 64);
    uint4* wl = (uint4*)(Wl + n * PITCH2 + h * 64);
    #pragma unroll
    for (int i = 0; i < 8; ++i) wl[i] = wr[i];
  }
  __syncthreads();

  for (int tile = blockIdx.x; tile < NTILES; tile += gridDim.x) {
    int bb = tile >> 8;
    int s0 = (tile & 255) * 4;
    size_t qg = (size_t)bb * S_ + s0 + w;

    const u16x8* yr0 = (const u16x8*)(y + (qg * K_ + lm) * 128);
    const u16x8* yr1 = (const u16x8*)(y + (qg * K_ + 16 + lm) * 128);
    u16x8 raw0[4], raw1[4];
    #pragma unroll
    for (int kt = 0; kt < 4; ++kt) { raw0[kt] = yr0[kt * 4 + lg]; raw1[kt] = yr1[kt * 4 + lg]; }
    bf16x8 a0[4], a1[4];
    #pragma unroll
    for (int kt = 0; kt < 4; ++kt) {
      int c = kt * 32 + lg * 8;
      f32x4 A0 = *(const f32x4*)&sa[c], A1 = *(const f32x4*)&sa[c + 4];
      f32x4 D0 = *(const f32x4*)&sd[c], D1 = *(const f32x4*)&sd[c + 4];
      #pragma unroll
      for (int j = 0; j < 4; ++j) {
        a0[kt][j]     = (short)f2bf(fmaxf(A0[j] * bf2f(raw0[kt][j])     + D0[j], 0.f));
        a0[kt][j + 4] = (short)f2bf(fmaxf(A1[j] * bf2f(raw0[kt][j + 4]) + D1[j], 0.f));
        a1[kt][j]     = (short)f2bf(fmaxf(A0[j] * bf2f(raw1[kt][j])     + D0[j], 0.f));
        a1[kt][j + 4] = (short)f2bf(fmaxf(A1[j] * bf2f(raw1[kt][j + 4]) + D1[j], 0.f));
      }
    }
    f32x4 acc[2][8];
    #pragma unroll
    for (int mi = 0; mi < 2; ++mi)
      #pragma unroll
      for (int nt = 0; nt < 8; ++nt) acc[mi][nt] = (f32x4){0.f, 0.f, 0.f, 0.f};
    #pragma unroll
    for (int kt = 0; kt < 4; ++kt) {
      int ko = kt * 32 + lg * 8;
      bf16x8 bv[8];
      #pragma unroll
      for (int nt = 0; nt < 8; ++nt)
        bv[nt] = *(const bf16x8*)&Wl[(nt * 16 + lm) * PITCH2 + ko];
      #pragma unroll
      for (int nt = 0; nt < 8; ++nt) {
        acc[0][nt] = MFMA(a0[kt], bv[nt], acc[0][nt]);
        acc[1][nt] = MFMA(a1[kt], bv[nt], acc[1][nt]);
      }
    }
    int slot = tile & 31;
    #pragma unroll
    for (int nt = 0; nt < 8; ++nt) {
      int col = nt * 16 + lm;
      int o = nh * 128 + col;
      float bo = sbias[col];
      float s1 = 0.f, s2 = 0.f, mx = -3.4e38f, mn = 3.4e38f;
      #pragma unroll
      for (int mi = 0; mi < 2; ++mi)
        #pragma unroll
        for (int r = 0; r < 4; ++r) {
          float yv = acc[mi][nt][r] + bo;
          s1 += yv; s2 += yv * yv;
          mx = fmaxf(mx, yv); mn = fminf(mn, yv);
        }
      s1 += __shfl_xor(s1, 16); s2 += __shfl_xor(s2, 16);
      s1 += __shfl_xor(s1, 32); s2 += __shfl_xor(s2, 32);
      mx = fmaxf(mx, __shfl_xor(mx, 16)); mx = fmaxf(mx, __shfl_xor(mx, 32));
      mn = fminf(mn, __shfl_xor(mn, 16)); mn = fminf(mn, __shfl_xor(mn, 32));
      if (lg == 0) {
        ymax[qg * 256 + o] = f2bf(mx);
        ymin[qg * 256 + o] = f2bf(mn);
        atomicAdd(stats3 + ((size_t)slot * 256 + o) * 2, s1);
        atomicAdd(stats3 + ((size_t)slot * 256 + o) * 2 + 1, s2);
      }
    }
  }
}

// -------- final: murs fold + select extreme by sign(a) + BN+relu + transpose --------
__global__ __launch_bounds__(256) void k_final(const unsigned short* __restrict__ ymax,
                                               const unsigned short* __restrict__ ymin,
                                               const float* __restrict__ stats3,
                                               const float* __restrict__ gamma,
                                               const float* __restrict__ beta,
                                               float* __restrict__ out2) {
  __shared__ float tile[32][33];
  __shared__ float smA[32], smD[32];
  int b = blockIdx.z, o0 = blockIdx.y * 32, s0 = blockIdx.x * 32;
  int tx = threadIdx.x, ty = threadIdx.y;
  if (ty == 0) {
    int c = o0 + tx;
    float s1 = 0.0f, s2 = 0.0f;
    for (int sl = 0; sl < 32; ++sl) {
      s1 += stats3[((size_t)sl * 256 + c) * 2];
      s2 += stats3[((size_t)sl * 256 + c) * 2 + 1];
    }
    const float inv = 1.0f / 524288.0f;
    float mu = s1 * inv;
    float var = s2 * inv - mu * mu;
    float a = gamma[c] * rsqrtf(var + 1e-5f);
    smA[tx] = a;
    smD[tx] = beta[c] - a * mu;
  }
  __syncthreads();
  float a_rd = smA[tx];
  #pragma unroll
  for (int j = 0; j < 32; j += 8) {
    size_t src = ((size_t)b * S_ + s0 + ty + j) * 256 + o0 + tx;
    tile[ty + j][tx] = (a_rd >= 0.0f) ? bf2f(ymax[src]) : bf2f(ymin[src]);
  }
  __syncthreads();
  #pragma unroll
  for (int j = 0; j < 32; j += 8) {
    float a = smA[ty + j], dd = smD[ty + j];
    out2[((size_t)b * 256 + o0 + ty + j) * S_ + s0 + tx] = fmaxf(a * tile[tx][ty + j] + dd, 0.0f);
  }
}

extern "C" void kernel_launch(void* const* d_in, const int* in_sizes, int n_in,
                              void* d_out, int out_size, void* d_ws, size_t ws_size,
                              hipStream_t stream) {
  (void)in_sizes; (void)n_in; (void)out_size; (void)ws_size;
  const float* xyz  = (const float*)d_in[0];
  const float* feat = (const float*)d_in[1];
  const float* w0   = (const float*)d_in[2];
  const float* b0   = (const float*)d_in[3];
  const float* ga0  = (const float*)d_in[4];
  const float* be0  = (const float*)d_in[5];
  const float* w1   = (const float*)d_in[6];
  const float* b1   = (const float*)d_in[7];
  const float* ga1  = (const float*)d_in[8];
  const float* be1  = (const float*)d_in[9];
  const float* w2   = (const float*)d_in[10];
  const float* b2   = (const float*)d_in[11];
  const float* ga2  = (const float*)d_in[12];
  const float* be2  = (const float*)d_in[13];

  float* out_xyz  = (float*)d_out;
  float* out_feat = out_xyz + (size_t)B_ * S_ * 3;

  char* ws = (char*)d_ws;
  size_t off = 0;
  auto alloc = [&](size_t bytes) -> void* {
    void* p = ws + off;
    off += (bytes + 255) & ~(size_t)255;
    return p;
  };
  unsigned short* featT = (unsigned short*)alloc((size_t)B_ * N_ * 128 * 2);  // 16.8 MB bf16
  int*   ball  = (int*)alloc((size_t)B_ * S_ * K_ * 4);                       // 2.1 MB
  float* stats = (float*)alloc(32768 * 4);
  unsigned short* wbf0 = (unsigned short*)alloc(128 * 160 * 2);
  unsigned short* wbf1 = (unsigned short*)alloc(128 * 128 * 2);
  unsigned short* wbf2 = (unsigned short*)alloc(256 * 128 * 2);
  unsigned short* ymaxb = (unsigned short*)alloc((size_t)B_ * S_ * 256 * 2);  // 8.4 MB
  unsigned short* yminb = (unsigned short*)alloc((size_t)B_ * S_ * 256 * 2);  // 8.4 MB
  unsigned short* y = (unsigned short*)alloc((size_t)B_ * S_ * K_ * 128 * 2); // 134 MB

  // blocks: 16 fps | 16 init | 8192 transpose
  k_front<<<16 + 16 + 8192, 512, 0, stream>>>(xyz, out_xyz, feat, featT,
                                              w0, w1, w2, wbf0, wbf1, wbf2, stats);
  k_ballq<<<dim3(256, 16), 256, 0, stream>>>(xyz, out_xyz, ball);
  // persistent grids: layer1 3 blocks/CU (43KB LDS), layer2 4/CU, layer3 (512,2)
  k_layer1<<<768, 256, 0, stream>>>(xyz, out_xyz, featT, ball, wbf0, b0, y, stats);
  k_layer2<<<1024, 256, 0, stream>>>(y, stats, ga0, be0, wbf1, b1, stats + 8192);
  k_layer3<<<dim3(512, 2), 256, 0, stream>>>(y, stats + 8192, ga1, be1, wbf2, b2,
                                             ymaxb, yminb, stats + 16384);
  k_final<<<dim3(32, 8, 16), dim3(32, 8), 0, stream>>>(ymaxb, yminb, stats + 16384,
                                                       ga2, be2, out_feat);
}

// Round 6
// 978.887 us; speedup vs baseline: 1.4963x; 1.0444x over previous
//
#include <hip/hip_runtime.h>

#define B_ 16
#define N_ 4096
#define S_ 1024
#define K_ 32
#define PITCH2 136   // 128 + 8 shorts: b128 frag reads -> 2-way bank alias (free)
#define PITCH1 168   // 160 + 8 shorts

typedef unsigned long long u64;
typedef short bf16x8 __attribute__((ext_vector_type(8)));
typedef unsigned short u16x8 __attribute__((ext_vector_type(8)));
typedef float f32x4 __attribute__((ext_vector_type(4)));
typedef float f32x2 __attribute__((ext_vector_type(2)));

__device__ __forceinline__ unsigned short f2bf(float f) {
  unsigned u = __float_as_uint(f);
  unsigned r = (u + 0x7FFFu + ((u >> 16) & 1u)) >> 16;
  return (unsigned short)r;
}
__device__ __forceinline__ float bf2f(unsigned short h) {
  return __uint_as_float(((unsigned)h) << 16);
}

// DPP row max: shr1,2,4,8 -> lanes 15/31/47/63 hold their 16-lane row max
#define DPP_MAX(v, ctrl)                                                        \
  {                                                                             \
    int _t = __builtin_amdgcn_update_dpp(__float_as_int(v), __float_as_int(v),  \
                                         ctrl, 0xf, 0xf, false);                \
    v = fmaxf(v, __int_as_float(_t));                                           \
  }

// ===== fused front kernel: blocks 0-15 FPS | 16-31 init | 32+ transpose =====
// FPS: proven 8-wave x 8-pt structure + R5 atomicMax key exchange (588us).
// R6: SALU wave-max tail — distances >= 0 so float bits are u32-monotone:
// 4 DPP row-max steps + readlane(15,31,47,63) + 3x s_max_u32 puts wmax in an
// SGPR (free broadcast, off the VALU pipe) instead of 2 more serial DPP + a
// readlane. Selection sequence & tie-break bit-identical.
__global__ __launch_bounds__(512) void k_front(
    const float* __restrict__ xyz, float* __restrict__ new_xyz,
    const float* __restrict__ feat, unsigned short* __restrict__ featT,
    const float* __restrict__ w0, const float* __restrict__ w1,
    const float* __restrict__ w2, unsigned short* __restrict__ wbf0,
    unsigned short* __restrict__ wbf1, unsigned short* __restrict__ wbf2,
    float* __restrict__ stats) {
  __shared__ __align__(16) float smem[N_ * 4 + S_ + 64];
  int blk = blockIdx.x, t = threadIdx.x;

  if (blk < 16) {
#pragma clang fp contract(off)
#if __has_builtin(__builtin_amdgcn_s_setprio)
    __builtin_amdgcn_s_setprio(3);
#endif
    float4* pts = (float4*)smem;
    int* idxs = (int*)(smem + N_ * 4);
    u64* km = (u64*)(smem + N_ * 4 + S_);   // 3 rotating max-key slots
    int b = blk;
    const float* base = xyz + (size_t)b * N_ * 3;
    for (int i = t; i < N_; i += 512)
      pts[i] = make_float4(base[i * 3], base[i * 3 + 1], base[i * 3 + 2], 0.0f);
    if (t == 0) { idxs[0] = 0; km[0] = 0; km[1] = 0; km[2] = 0; }
    __syncthreads();
    f32x2 px[4], py[4], pz[4], pd[4];
    int i0 = t * 8;
    #pragma unroll
    for (int j = 0; j < 4; ++j) {
      float4 p0 = pts[i0 + 2 * j], p1 = pts[i0 + 2 * j + 1];
      px[j] = (f32x2){p0.x, p1.x};
      py[j] = (f32x2){p0.y, p1.y};
      pz[j] = (f32x2){p0.z, p1.z};
      pd[j] = (f32x2){1e10f, 1e10f};
    }
    int cur = 0;
    int sl = 0;
    for (int it = 0; it < S_; ++it) {
      float4 c = pts[cur];
      f32x2 c2x = (f32x2){c.x, c.x}, c2y = (f32x2){c.y, c.y}, c2z = (f32x2){c.z, c.z};
      float bestv = -1.0f; int besti = 0;
      #pragma unroll
      for (int j = 0; j < 4; ++j) {
        f32x2 dx = px[j] - c2x;
        f32x2 dy = py[j] - c2y;
        f32x2 dz = pz[j] - c2z;
        f32x2 d = (dx * dx + dy * dy) + dz * dz;
        f32x2 dm = __builtin_elementwise_min(pd[j], d);
        pd[j] = dm;
        if (dm.x > bestv) { bestv = dm.x; besti = 2 * j; }
        if (dm.y > bestv) { bestv = dm.y; besti = 2 * j + 1; }
      }
      float v = bestv;
      DPP_MAX(v, 0x111);
      DPP_MAX(v, 0x112);
      DPP_MAX(v, 0x114);
      DPP_MAX(v, 0x118);
      // SALU tail: rows' maxima -> s_max_u32 (bits monotone for dist >= 0)
      unsigned r0 = (unsigned)__builtin_amdgcn_readlane(__float_as_int(v), 15);
      unsigned r1 = (unsigned)__builtin_amdgcn_readlane(__float_as_int(v), 31);
      unsigned r2 = (unsigned)__builtin_amdgcn_readlane(__float_as_int(v), 47);
      unsigned r3 = (unsigned)__builtin_amdgcn_readlane(__float_as_int(v), 63);
      unsigned ra = r0 > r1 ? r0 : r1;
      unsigned rb = r2 > r3 ? r2 : r3;
      unsigned wmaxb = ra > rb ? ra : rb;
      float wmax = __uint_as_float(wmaxb);
      u64 mask = __ballot(bestv == wmax);
      int owner = __ffsll((long long)mask) - 1;
      int widx = __builtin_amdgcn_readlane(i0 + besti, owner);
      if ((t & 63) == 0)
        atomicMax((unsigned long long*)&km[sl],
                  ((u64)wmaxb << 32) | (unsigned)(4095 - widx));
      __syncthreads();
      u64 k0 = km[sl];   // uniform-address broadcast read
      cur = 4095 - (int)(unsigned)(k0 & 0xFFFFFFFFull);
      if (t == 0) {
        if (it + 1 < S_) idxs[it + 1] = cur;
        km[sl == 0 ? 2 : sl - 1] = 0;   // reset slot (sl+2)%3 for iter it+2
      }
      sl = (sl == 2) ? 0 : sl + 1;
    }
    __syncthreads();
    for (int i = t; i < S_; i += 512) {
      float4 v = pts[idxs[i]];
      size_t o = ((size_t)b * S_ + i) * 3;
      new_xyz[o] = v.x; new_xyz[o + 1] = v.y; new_xyz[o + 2] = v.z;
    }
  } else if (blk < 32) {
    int id = (blk - 16) * 512 + t;
    const int st = 16 * 512;
    for (int i = id; i < 32768; i += st) stats[i] = 0.0f;
    for (int i = id; i < 128 * 160; i += st) {
      int n = i / 160, k = i - n * 160;
      float v = (k < 128) ? w0[n * 131 + 3 + k] : (k < 131) ? w0[n * 131 + k - 128] : 0.0f;
      wbf0[i] = f2bf(v);
    }
    for (int i = id; i < 128 * 128; i += st) wbf1[i] = f2bf(w1[i]);
    for (int i = id; i < 256 * 128; i += st) wbf2[i] = f2bf(w2[i]);
  } else {
    float (*tile)[33] = (float(*)[33])smem;
    int blk2 = blk - 32;
    int n0 = (blk2 & 127) * 32;
    int c0 = ((blk2 >> 7) & 3) * 32;
    int b = blk2 >> 9;
    int tx = t & 31, ty = t >> 5;
    #pragma unroll
    for (int j = 0; j < 32; j += 16)
      tile[ty + j][tx] = feat[((size_t)b * 128 + c0 + ty + j) * N_ + n0 + tx];
    __syncthreads();
    #pragma unroll
    for (int j = 0; j < 32; j += 16)
      featT[((size_t)b * N_ + n0 + ty + j) * 128 + c0 + tx] = f2bf(tile[tx][ty + j]);
  }
}

// ---------------- ball query (standalone; bit-exact formula) ----------------
__global__ __launch_bounds__(256) void k_ballq(const float* __restrict__ xyz,
                                               const float* __restrict__ new_xyz,
                                               int* __restrict__ ball_idx) {
  int b = blockIdx.y;
  int s = blockIdx.x * 4 + (threadIdx.x >> 6);
  int lane = threadIdx.x & 63;
  const float* pb = xyz + (size_t)b * N_ * 3;
  size_t q = (size_t)b * S_ + s;
  float qx = new_xyz[q * 3], qy = new_xyz[q * 3 + 1], qz = new_xyz[q * 3 + 2];
  float sq = __fadd_rn(__fadd_rn(__fmul_rn(qx, qx), __fmul_rn(qy, qy)), __fmul_rn(qz, qz));
  int* out = ball_idx + q * K_;
  int total = 0;
  int first_idx = -1;
  for (int basei = 0; basei < N_; basei += 64) {
    int i = basei + lane;
    float fx = pb[i * 3], fy = pb[i * 3 + 1], fz = pb[i * 3 + 2];
    float dot = __fmul_rn(qx, fx);
    dot = __fadd_rn(dot, __fmul_rn(qy, fy));
    dot = __fadd_rn(dot, __fmul_rn(qz, fz));
    float sd = __fadd_rn(__fadd_rn(__fmul_rn(fx, fx), __fmul_rn(fy, fy)), __fmul_rn(fz, fz));
    float dist = __fadd_rn(__fadd_rn(__fmul_rn(-2.0f, dot), sq), sd);
    bool within = (dist <= 0.36f);
    u64 m = __ballot(within);
    if (first_idx < 0 && m) first_idx = basei + __ffsll((long long)m) - 1;
    if (within) {
      int pos = total + __popcll(m & ((1ull << lane) - 1ull));
      if (pos < K_) out[pos] = i;
    }
    total += (int)__popcll(m);
    if (total >= K_) break;
  }
  if (total < K_) {
    int k2 = total + lane;
    if (k2 < K_) out[k2] = first_idx;
  }
}

// ==== MFMA layer kernels — persistent blocks: W/murs staged ONCE, then a
// barrier-free tile loop (A lives in registers since r10) ====
#define MFMA(a, b, c) __builtin_amdgcn_mfma_f32_16x16x32_bf16(a, b, c, 0, 0, 0)
#define NTILES 4096   // 16 batches x 256 s0-tiles

// ---- layer 1: gather(reg) + matmul K=131(pad160)->128 ----
__global__ __launch_bounds__(256) void k_layer1(
    const float* __restrict__ xyz, const float* __restrict__ new_xyz,
    const unsigned short* __restrict__ featT, const int* __restrict__ ball_idx,
    const unsigned short* __restrict__ wbf0, const float* __restrict__ b0,
    unsigned short* __restrict__ y, float* __restrict__ stats) {
  __shared__ __align__(16) unsigned short Wl[128 * PITCH1];   // 42 KB, W only
  __shared__ float sbias[128];
  int t = threadIdx.x;
  int w = t >> 6, L = t & 63, lm = L & 15, lg = L >> 4;
  {
    int n = t >> 1, h = t & 1;
    const uint4* wr = (const uint4*)(wbf0 + n * 160 + h * 80);
    uint4* wl = (uint4*)(Wl + n * PITCH1 + h * 80);
    #pragma unroll
    for (int i = 0; i < 10; ++i) wl[i] = wr[i];
    if (t < 128) sbias[t] = b0[t];
  }
  __syncthreads();

  for (int tile = blockIdx.x; tile < NTILES; tile += gridDim.x) {
    int bb = tile >> 8;
    int s0 = (tile & 255) * 4;
    size_t qg = (size_t)bb * S_ + s0 + w;

    int p0 = ball_idx[qg * K_ + lm];
    int p1 = ball_idx[qg * K_ + 16 + lm];
    const unsigned short* f0 = featT + ((size_t)bb * N_ + p0) * 128;
    const unsigned short* f1 = featT + ((size_t)bb * N_ + p1) * 128;
    bf16x8 a0[5], a1[5];
    #pragma unroll
    for (int kt = 0; kt < 4; ++kt) {
      a0[kt] = *(const bf16x8*)(f0 + kt * 32 + lg * 8);
      a1[kt] = *(const bf16x8*)(f1 + kt * 32 + lg * 8);
    }
    a0[4] = (bf16x8){0, 0, 0, 0, 0, 0, 0, 0};
    a1[4] = (bf16x8){0, 0, 0, 0, 0, 0, 0, 0};
    if (lg == 0) {
      float nx = new_xyz[qg * 3], ny = new_xyz[qg * 3 + 1], nz = new_xyz[qg * 3 + 2];
      const float* pp0 = xyz + ((size_t)bb * N_ + p0) * 3;
      const float* pp1 = xyz + ((size_t)bb * N_ + p1) * 3;
      a0[4][0] = (short)f2bf(pp0[0] - nx);
      a0[4][1] = (short)f2bf(pp0[1] - ny);
      a0[4][2] = (short)f2bf(pp0[2] - nz);
      a1[4][0] = (short)f2bf(pp1[0] - nx);
      a1[4][1] = (short)f2bf(pp1[1] - ny);
      a1[4][2] = (short)f2bf(pp1[2] - nz);
    }
    f32x4 acc[2][8];
    #pragma unroll
    for (int mi = 0; mi < 2; ++mi)
      #pragma unroll
      for (int nt = 0; nt < 8; ++nt) acc[mi][nt] = (f32x4){0.f, 0.f, 0.f, 0.f};
    #pragma unroll
    for (int kt = 0; kt < 5; ++kt) {
      int ko = kt * 32 + lg * 8;
      bf16x8 bv[8];
      #pragma unroll
      for (int nt = 0; nt < 8; ++nt)
        bv[nt] = *(const bf16x8*)&Wl[(nt * 16 + lm) * PITCH1 + ko];
      #pragma unroll
      for (int nt = 0; nt < 8; ++nt) {
        acc[0][nt] = MFMA(a0[kt], bv[nt], acc[0][nt]);
        acc[1][nt] = MFMA(a1[kt], bv[nt], acc[1][nt]);
      }
    }
    int slot = tile & 31;
    #pragma unroll
    for (int nt = 0; nt < 8; ++nt) {
      int col = nt * 16 + lm;
      float bo = sbias[col];
      float s1 = 0.f, s2 = 0.f;
      #pragma unroll
      for (int mi = 0; mi < 2; ++mi)
        #pragma unroll
        for (int r = 0; r < 4; ++r) {
          float yv = acc[mi][nt][r] + bo;
          s1 += yv; s2 += yv * yv;
          int ks = mi * 16 + lg * 4 + r;
          y[(qg * K_ + ks) * 128 + col] = f2bf(yv);
        }
      s1 += __shfl_xor(s1, 16); s2 += __shfl_xor(s2, 16);
      s1 += __shfl_xor(s1, 32); s2 += __shfl_xor(s2, 32);
      if (lg == 0) {
        atomicAdd(stats + ((size_t)slot * 128 + col) * 2, s1);
        atomicAdd(stats + ((size_t)slot * 128 + col) * 2 + 1, s2);
      }
    }
  }
}

// ---- layer 2: murs fold + BN+relu(reg) + matmul 128->128, y IN-PLACE ----
__global__ __launch_bounds__(256) void k_layer2(
    unsigned short* y, const float* __restrict__ stats,
    const float* __restrict__ gamma, const float* __restrict__ beta,
    const unsigned short* __restrict__ wbf1, const float* __restrict__ b1,
    float* __restrict__ stats2) {
  __shared__ __align__(16) unsigned short Wl[128 * PITCH2];   // 34 KB, W only
  __shared__ __align__(16) float sa[128], sd[128];
  __shared__ float sbias[128];
  int t = threadIdx.x;
  int w = t >> 6, L = t & 63, lm = L & 15, lg = L >> 4;
  if (t < 128) {
    float s1 = 0.0f, s2 = 0.0f;
    for (int sl = 0; sl < 32; ++sl) {
      s1 += stats[((size_t)sl * 128 + t) * 2];
      s2 += stats[((size_t)sl * 128 + t) * 2 + 1];
    }
    const float inv = 1.0f / 524288.0f;
    float mu = s1 * inv;
    float var = s2 * inv - mu * mu;
    float a = gamma[t] * rsqrtf(var + 1e-5f);
    sa[t] = a;
    sd[t] = beta[t] - a * mu;
    sbias[t] = b1[t];
  }
  {
    int n = t >> 1, h = t & 1;
    const uint4* wr = (const uint4*)(wbf1 + n * 128 + h * 64);
    uint4* wl = (uint4*)(Wl + n * PITCH2 + h * 64);
    #pragma unroll
    for (int i = 0; i < 8; ++i) wl[i] = wr[i];
  }
  __syncthreads();

  for (int tile = blockIdx.x; tile < NTILES; tile += gridDim.x) {
    int bb = tile >> 8;
    int s0 = (tile & 255) * 4;
    size_t qg = (size_t)bb * S_ + s0 + w;

    const u16x8* yr0 = (const u16x8*)(y + (qg * K_ + lm) * 128);
    const u16x8* yr1 = (const u16x8*)(y + (qg * K_ + 16 + lm) * 128);
    u16x8 raw0[4], raw1[4];
    #pragma unroll
    for (int kt = 0; kt < 4; ++kt) { raw0[kt] = yr0[kt * 4 + lg]; raw1[kt] = yr1[kt * 4 + lg]; }
    bf16x8 a0[4], a1[4];
    #pragma unroll
    for (int kt = 0; kt < 4; ++kt) {
      int c = kt * 32 + lg * 8;
      f32x4 A0 = *(const f32x4*)&sa[c], A1 = *(const f32x4*)&sa[c + 4];
      f32x4 D0 = *(const f32x4*)&sd[c], D1 = *(const f32x4*)&sd[c + 4];
      #pragma unroll
      for (int j = 0; j < 4; ++j) {
        a0[kt][j]     = (short)f2bf(fmaxf(A0[j] * bf2f(raw0[kt][j])     + D0[j], 0.f));
        a0[kt][j + 4] = (short)f2bf(fmaxf(A1[j] * bf2f(raw0[kt][j + 4]) + D1[j], 0.f));
        a1[kt][j]     = (short)f2bf(fmaxf(A0[j] * bf2f(raw1[kt][j])     + D0[j], 0.f));
        a1[kt][j + 4] = (short)f2bf(fmaxf(A1[j] * bf2f(raw1[kt][j + 4]) + D1[j], 0.f));
      }
    }
    f32x4 acc[2][8];
    #pragma unroll
    for (int mi = 0; mi < 2; ++mi)
      #pragma unroll
      for (int nt = 0; nt < 8; ++nt) acc[mi][nt] = (f32x4){0.f, 0.f, 0.f, 0.f};
    #pragma unroll
    for (int kt = 0; kt < 4; ++kt) {
      int ko = kt * 32 + lg * 8;
      bf16x8 bv[8];
      #pragma unroll
      for (int nt = 0; nt < 8; ++nt)
        bv[nt] = *(const bf16x8*)&Wl[(nt * 16 + lm) * PITCH2 + ko];
      #pragma unroll
      for (int nt = 0; nt < 8; ++nt) {
        acc[0][nt] = MFMA(a0[kt], bv[nt], acc[0][nt]);
        acc[1][nt] = MFMA(a1[kt], bv[nt], acc[1][nt]);
      }
    }
    int slot = tile & 31;
    #pragma unroll
    for (int nt = 0; nt < 8; ++nt) {
      int col = nt * 16 + lm;
      float bo = sbias[col];
      float s1 = 0.f, s2 = 0.f;
      #pragma unroll
      for (int mi = 0; mi < 2; ++mi)
        #pragma unroll
        for (int r = 0; r < 4; ++r) {
          float yv = acc[mi][nt][r] + bo;
          s1 += yv; s2 += yv * yv;
          int ks = mi * 16 + lg * 4 + r;
          y[(qg * K_ + ks) * 128 + col] = f2bf(yv);
        }
      s1 += __shfl_xor(s1, 16); s2 += __shfl_xor(s2, 16);
      s1 += __shfl_xor(s1, 32); s2 += __shfl_xor(s2, 32);
      if (lg == 0) {
        atomicAdd(stats2 + ((size_t)slot * 128 + col) * 2, s1);
        atomicAdd(stats2 + ((size_t)slot * 128 + col) * 2 + 1, s2);
      }
    }
  }
}

// ---- layer 3: murs fold + BN+relu(reg) + matmul 128->256, BOTH output
// halves per block (R6): y-tile read + BN/relu conversion done ONCE, W2 fully
// staged (256 rows, 68KB LDS -> 2 blocks/CU), halves y traffic vs (512,2). ----
__global__ __launch_bounds__(256) void k_layer3(
    const unsigned short* __restrict__ y, const float* __restrict__ stats2,
    const float* __restrict__ gamma, const float* __restrict__ beta,
    const unsigned short* __restrict__ wbf2, const float* __restrict__ b2,
    unsigned short* __restrict__ ymax, unsigned short* __restrict__ ymin,
    float* __restrict__ stats3) {
  __shared__ __align__(16) unsigned short Wl[256 * PITCH2];   // 68 KB
  __shared__ __align__(16) float sa[128], sd[128];
  __shared__ float sbias[256];
  int t = threadIdx.x;
  int w = t >> 6, L = t & 63, lm = L & 15, lg = L >> 4;
  if (t < 128) {
    float s1 = 0.0f, s2 = 0.0f;
    for (int sl = 0; sl < 32; ++sl) {
      s1 += stats2[((size_t)sl * 128 + t) * 2];
      s2 += stats2[((size_t)sl * 128 + t) * 2 + 1];
    }
    const float inv = 1.0f / 524288.0f;
    float mu = s1 * inv;
    float var = s2 * inv - mu * mu;
    float a = gamma[t] * rsqrtf(var + 1e-5f);
    sa[t] = a;
    sd[t] = beta[t] - a * mu;
  }
  sbias[t] = b2[t];
  {
    // stage all 256 W2 rows: thread t loads row t (16 uint4)
    const uint4* wr = (const uint4*)(wbf2 + (size_t)t * 128);
    uint4* wl = (uint4*)(Wl + t * PITCH2);
    #pragma unroll
    for (int i = 0; i < 16; ++i) wl[i] = wr[i];
  }
  __syncthreads();

  for (int tile = blockIdx.x; tile < NTILES; tile += gridDim.x) {
    int bb = tile >> 8;
    int s0 = (tile & 255) * 4;
    size_t qg = (size_t)bb * S_ + s0 + w;

    const u16x8* yr0 = (const u16x8*)(y + (qg * K_ + lm) * 128);
    const u16x8* yr1 = (const u16x8*)(y + (qg * K_ + 16 + lm) * 128);
    u16x8 raw0[4], raw1[4];
    #pragma unroll
    for (int kt = 0; kt < 4; ++kt) { raw0[kt] = yr0[kt * 4 + lg]; raw1[kt] = yr1[kt * 4 + lg]; }
    bf16x8 a0[4], a1[4];
    #pragma unroll
    for (int kt = 0; kt < 4; ++kt) {
      int c = kt * 32 + lg * 8;
      f32x4 A0 = *(const f32x4*)&sa[c], A1 = *(const f32x4*)&sa[c + 4];
      f32x4 D0 = *(const f32x4*)&sd[c], D1 = *(const f32x4*)&sd[c + 4];
      #pragma unroll
      for (int j = 0; j < 4; ++j) {
        a0[kt][j]     = (short)f2bf(fmaxf(A0[j] * bf2f(raw0[kt][j])     + D0[j], 0.f));
        a0[kt][j + 4] = (short)f2bf(fmaxf(A1[j] * bf2f(raw0[kt][j + 4]) + D1[j], 0.f));
        a1[kt][j]     = (short)f2bf(fmaxf(A0[j] * bf2f(raw1[kt][j])     + D0[j], 0.f));
        a1[kt][j + 4] = (short)f2bf(fmaxf(A1[j] * bf2f(raw1[kt][j + 4]) + D1[j], 0.f));
      }
    }
    int slot = tile & 31;
    #pragma unroll
    for (int h = 0; h < 2; ++h) {
      f32x4 acc[2][8];
      #pragma unroll
      for (int mi = 0; mi < 2; ++mi)
        #pragma unroll
        for (int nt = 0; nt < 8; ++nt) acc[mi][nt] = (f32x4){0.f, 0.f, 0.f, 0.f};
      #pragma unroll
      for (int kt = 0; kt < 4; ++kt) {
        int ko = kt * 32 + lg * 8;
        bf16x8 bv[8];
        #pragma unroll
        for (int nt = 0; nt < 8; ++nt)
          bv[nt] = *(const bf16x8*)&Wl[(h * 128 + nt * 16 + lm) * PITCH2 + ko];
        #pragma unroll
        for (int nt = 0; nt < 8; ++nt) {
          acc[0][nt] = MFMA(a0[kt], bv[nt], acc[0][nt]);
          acc[1][nt] = MFMA(a1[kt], bv[nt], acc[1][nt]);
        }
      }
      #pragma unroll
      for (int nt = 0; nt < 8; ++nt) {
        int col = nt * 16 + lm;
        int o = h * 128 + col;
        float bo = sbias[o];
        float s1 = 0.f, s2 = 0.f, mx = -3.4e38f, mn = 3.4e38f;
        #pragma unroll
        for (int mi = 0; mi < 2; ++mi)
          #pragma unroll
          for (int r = 0; r < 4; ++r) {
            float yv = acc[mi][nt][r] + bo;
            s1 += yv; s2 += yv * yv;
            mx = fmaxf(mx, yv); mn = fminf(mn, yv);
          }
        s1 += __shfl_xor(s1, 16); s2 += __shfl_xor(s2, 16);
        s1 += __shfl_xor(s1, 32); s2 += __shfl_xor(s2, 32);
        mx = fmaxf(mx, __shfl_xor(mx, 16)); mx = fmaxf(mx, __shfl_xor(mx, 32));
        mn = fminf(mn, __shfl_xor(mn, 16)); mn = fminf(mn, __shfl_xor(mn, 32));
        if (lg == 0) {
          ymax[qg * 256 + o] = f2bf(mx);
          ymin[qg * 256 + o] = f2bf(mn);
          atomicAdd(stats3 + ((size_t)slot * 256 + o) * 2, s1);
          atomicAdd(stats3 + ((size_t)slot * 256 + o) * 2 + 1, s2);
        }
      }
    }
  }
}

// -------- final: murs fold + select extreme by sign(a) + BN+relu + transpose --------
__global__ __launch_bounds__(256) void k_final(const unsigned short* __restrict__ ymax,
                                               const unsigned short* __restrict__ ymin,
                                               const float* __restrict__ stats3,
                                               const float* __restrict__ gamma,
                                               const float* __restrict__ beta,
                                               float* __restrict__ out2) {
  __shared__ float tile[32][33];
  __shared__ float smA[32], smD[32];
  int b = blockIdx.z, o0 = blockIdx.y * 32, s0 = blockIdx.x * 32;
  int tx = threadIdx.x, ty = threadIdx.y;
  if (ty == 0) {
    int c = o0 + tx;
    float s1 = 0.0f, s2 = 0.0f;
    for (int sl = 0; sl < 32; ++sl) {
      s1 += stats3[((size_t)sl * 256 + c) * 2];
      s2 += stats3[((size_t)sl * 256 + c) * 2 + 1];
    }
    const float inv = 1.0f / 524288.0f;
    float mu = s1 * inv;
    float var = s2 * inv - mu * mu;
    float a = gamma[c] * rsqrtf(var + 1e-5f);
    smA[tx] = a;
    smD[tx] = beta[c] - a * mu;
  }
  __syncthreads();
  float a_rd = smA[tx];
  #pragma unroll
  for (int j = 0; j < 32; j += 8) {
    size_t src = ((size_t)b * S_ + s0 + ty + j) * 256 + o0 + tx;
    tile[ty + j][tx] = (a_rd >= 0.0f) ? bf2f(ymax[src]) : bf2f(ymin[src]);
  }
  __syncthreads();
  #pragma unroll
  for (int j = 0; j < 32; j += 8) {
    float a = smA[ty + j], dd = smD[ty + j];
    out2[((size_t)b * 256 + o0 + ty + j) * S_ + s0 + tx] = fmaxf(a * tile[tx][ty + j] + dd, 0.0f);
  }
}

extern "C" void kernel_launch(void* const* d_in, const int* in_sizes, int n_in,
                              void* d_out, int out_size, void* d_ws, size_t ws_size,
                              hipStream_t stream) {
  (void)in_sizes; (void)n_in; (void)out_size; (void)ws_size;
  const float* xyz  = (const float*)d_in[0];
  const float* feat = (const float*)d_in[1];
  const float* w0   = (const float*)d_in[2];
  const float* b0   = (const float*)d_in[3];
  const float* ga0  = (const float*)d_in[4];
  const float* be0  = (const float*)d_in[5];
  const float* w1   = (const float*)d_in[6];
  const float* b1   = (const float*)d_in[7];
  const float* ga1  = (const float*)d_in[8];
  const float* be1  = (const float*)d_in[9];
  const float* w2   = (const float*)d_in[10];
  const float* b2   = (const float*)d_in[11];
  const float* ga2  = (const float*)d_in[12];
  const float* be2  = (const float*)d_in[13];

  float* out_xyz  = (float*)d_out;
  float* out_feat = out_xyz + (size_t)B_ * S_ * 3;

  char* ws = (char*)d_ws;
  size_t off = 0;
  auto alloc = [&](size_t bytes) -> void* {
    void* p = ws + off;
    off += (bytes + 255) & ~(size_t)255;
    return p;
  };
  unsigned short* featT = (unsigned short*)alloc((size_t)B_ * N_ * 128 * 2);  // 16.8 MB bf16
  int*   ball  = (int*)alloc((size_t)B_ * S_ * K_ * 4);                       // 2.1 MB
  float* stats = (float*)alloc(32768 * 4);
  unsigned short* wbf0 = (unsigned short*)alloc(128 * 160 * 2);
  unsigned short* wbf1 = (unsigned short*)alloc(128 * 128 * 2);
  unsigned short* wbf2 = (unsigned short*)alloc(256 * 128 * 2);
  unsigned short* ymaxb = (unsigned short*)alloc((size_t)B_ * S_ * 256 * 2);  // 8.4 MB
  unsigned short* yminb = (unsigned short*)alloc((size_t)B_ * S_ * 256 * 2);  // 8.4 MB
  unsigned short* y = (unsigned short*)alloc((size_t)B_ * S_ * K_ * 128 * 2); // 134 MB

  // blocks: 16 fps | 16 init | 8192 transpose
  k_front<<<16 + 16 + 8192, 512, 0, stream>>>(xyz, out_xyz, feat, featT,
                                              w0, w1, w2, wbf0, wbf1, wbf2, stats);
  k_ballq<<<dim3(256, 16), 256, 0, stream>>>(xyz, out_xyz, ball);
  // persistent grids: layer1 3/CU (43KB LDS), layer2 4/CU, layer3 2/CU (68KB)
  k_layer1<<<768, 256, 0, stream>>>(xyz, out_xyz, featT, ball, wbf0, b0, y, stats);
  k_layer2<<<1024, 256, 0, stream>>>(y, stats, ga0, be0, wbf1, b1, stats + 8192);
  k_layer3<<<512, 256, 0, stream>>>(y, stats + 8192, ga1, be1, wbf2, b2,
                                    ymaxb, yminb, stats + 16384);
  k_final<<<dim3(32, 8, 16), dim3(32, 8), 0, stream>>>(ymaxb, yminb, stats + 16384,
                                                       ga2, be2, out_feat);
}